// Round 13
// baseline (198.817 us; speedup 1.0000x reference)
//
#include <hip/hip_runtime.h>
#include <math.h>

#define BN 4
#define CDIM 256
#define NKP 1024
#define HH 128
#define WW 128
#define HWPX (HH*WW)

#define PSPLIT 32
#define PPB 512
#define NT 128

// ---- workspace layout ----
#define WS_RS 0
#define WS_RT (WS_RS + BN*NKP)
#define WS_PART (WS_RT + BN*HWPX)          // float4[BN*NKP*PSPLIT] = 2 MB @ byte 278528
#define WS_PQ_B 2375680u                   // [b][kc][64 frag]x1024B (+unused lo) = 4 MB
#define WS_PP_B 6569984u                   // [b][kc][1024 frag]x1024B (HI ONLY) = 32 MB
#define WS_NEED 40124416u

typedef __attribute__((ext_vector_type(8)))  _Float16 v8h;
typedef __attribute__((ext_vector_type(4)))  float v4f;

#define GETJ(v, j) ((j) == 0 ? (v).x : (j) == 1 ? (v).y : (j) == 2 ? (v).z : (v).w)

// ======================= fast path =======================

// Fused prep: blocks 0..255: P (dd) -> f16 HI plane. Blocks 256..271: Q (kd)
// -> f16 HI plane (1-term scheme; logit err ~5e-3 vs 0.5 bf16 output floor).
// Fragment block = 1024 B: [4 ko][16 col][16 B]; frag index = col>>4.
__global__ __launch_bounds__(256) void k_prep(const float* __restrict__ kd,
                                              const float* __restrict__ dd,
                                              float* __restrict__ wsf,
                                              char* __restrict__ pq,
                                              char* __restrict__ pp) {
  if (blockIdx.x < 256) {
    int id = blockIdx.x;                 // 256 = b*64 + mb
    int b = id >> 6;
    int m = (id & 63) * 256 + threadIdx.x;
    const float* p = dd + (size_t)(2 * b + 1) * CDIM * HWPX + m;
    char* mb = pp + (size_t)b * 8388608 + (m >> 4) * 1024 + (m & 15) * 16;
    float s = 0.f;
#pragma unroll
    for (int kc = 0; kc < 8; ++kc) {
#pragma unroll
      for (int ko = 0; ko < 4; ++ko) {
        v8h hi;
#pragma unroll
        for (int j = 0; j < 8; ++j) {
          float v = p[(size_t)(kc * 32 + ko * 8 + j) * HWPX];
          s = fmaf(v, v, s);
          hi[j] = (_Float16)(v * 32.f);
        }
        *(v8h*)(mb + (size_t)kc * 1048576 + ko * 256) = hi;
      }
    }
    wsf[WS_RT + b * HWPX + m] = 1.f / fmaxf(sqrtf(s), 1e-12f);
  } else {
    int id = blockIdx.x - 256;           // 16 = b*4 + nb
    int b = id >> 2;
    int n = (id & 3) * 256 + threadIdx.x;
    const float* p = kd + (size_t)(2 * b) * CDIM * NKP + n;
    char* qb = pq + (size_t)b * 1048576 + (n >> 4) * 1024 + (n & 15) * 16;
    float s = 0.f;
#pragma unroll
    for (int kc = 0; kc < 8; ++kc) {
#pragma unroll
      for (int ko = 0; ko < 4; ++ko) {
        v8h hi;
#pragma unroll
        for (int j = 0; j < 8; ++j) {
          float v = p[(size_t)(kc * 32 + ko * 8 + j) * NKP];
          s = fmaf(v, v, s);
          hi[j] = (_Float16)(v * 32.f);
        }
        *(v8h*)(qb + (size_t)kc * 131072 + ko * 256) = hi;
      }
    }
    wsf[WS_RS + b * NKP + n] = 1.f / fmaxf(sqrtf(s), 1e-12f);
  }
}

// Zero-LDS (merge-only) fused MFMA GEMM + fixed-shift softmax, 1-term f16.
// PSPLIT=32 -> grid 1024 = 4 blocks/CU, 4 waves/SIMD. Single-buffered
// fragments (TLP hides latency). P and Q stream from L2 as 1-KB wave loads.
#define LOADT(ph, qh, t) do {                                                  \
  const int pt_ = (t) >> 3, kc_ = (t) & 7;                                     \
  const char* Pb_ = ppb + (size_t)kc_ * 1048576 + (size_t)(frp + pt_ * 8) * 1024; \
  const char* Qb_ = pqb + (size_t)kc_ * 131072 + (size_t)frq * 1024;           \
  _Pragma("unroll")                                                            \
  for (int f_ = 0; f_ < 4; ++f_) {                                             \
    ph[f_] = *(const v8h*)(Pb_ + f_ * 1024 + lane16);                          \
    qh[f_] = *(const v8h*)(Qb_ + f_ * 1024 + lane16);                          \
  }                                                                            \
} while (0)

#define MFMAT(ph, qh)                                                          \
  __builtin_amdgcn_s_setprio(1);                                               \
  _Pragma("unroll")                                                            \
  for (int s_ = 0; s_ < 4; ++s_) {                                             \
    _Pragma("unroll")                                                          \
    for (int f_ = 0; f_ < 4; ++f_) {                                           \
      acc[f_][s_] = __builtin_amdgcn_mfma_f32_16x16x32_f16(ph[f_], qh[s_], acc[f_][s_], 0, 0, 0); \
    }                                                                          \
  }                                                                            \
  __builtin_amdgcn_s_setprio(0);

__global__ __launch_bounds__(256, 4) void k_match3(const char* __restrict__ pp,
                                                   const char* __restrict__ pq,
                                                   const float* __restrict__ wsf,
                                                   float4* __restrict__ partials) {
  __shared__ float4 red[NT][8];   // 16 KB merge buffer only
  const int tid = threadIdx.x;
  const int w = tid >> 6, lane = tid & 63;
  const int l15 = lane & 15, lq = lane >> 4;
  const int wm = w & 1, wn = w >> 1;

  // XCD-chunked grid: fid = b*256 + ps*8 + nt; XCD x owns b = x>>1, 16 ps.
  const int raw = blockIdx.x;
  const int fid = (raw & 7) * 128 + (raw >> 3);
  const int b = fid >> 8, ps = (fid >> 3) & 31, nt = fid & 7;
  const int n0b = nt * NT;

  const char* ppb = pp + (size_t)b * 8388608;
  const char* pqb = pq + (size_t)b * 1048576;
  const float* rtp = wsf + WS_RT + b * HWPX + ps * PPB;
  const float* rsp = wsf + WS_RS + b * NKP;

  const int frp = ps * 32 + wm * 4;
  const int frq = nt * 8 + wn * 4;
  const unsigned lane16 = (unsigned)lane * 16;

  float rs100[4];
#pragma unroll
  for (int s = 0; s < 4; ++s)
    rs100[s] = rsp[n0b + wn * 64 + s * 16 + l15] * (100.f / 1024.f);

  float ls[4], su[4], sv[4];
#pragma unroll
  for (int s = 0; s < 4; ++s) { ls[s] = su[s] = sv[s] = 0.f; }

  v4f acc[4][4];
#pragma unroll
  for (int f = 0; f < 4; ++f)
#pragma unroll
    for (int s = 0; s < 4; ++s)
#pragma unroll
      for (int e = 0; e < 4; ++e) acc[f][s][e] = 0.f;

  const float ubase = (float)(wm * 64 + lq * 4);
  const float vbase = (float)(ps * 4);

  v8h ph[4], qh[4];
#pragma unroll 8
  for (int t = 0; t < 32; ++t) {
    LOADT(ph, qh, t);
    MFMAT(ph, qh);

    if ((t & 7) == 7) {                  // K complete for this 128-px tile
      const int pt = t >> 3;
      const float vb = vbase + (float)pt;
      float4 rt4[4];
#pragma unroll
      for (int f = 0; f < 4; ++f)
        rt4[f] = *(const float4*)(rtp + pt * 128 + wm * 64 + f * 16 + lq * 4);
#pragma unroll
      for (int s = 0; s < 4; ++s) {
        float te = 0.f, tu = 0.f;
#pragma unroll
        for (int f = 0; f < 4; ++f)
#pragma unroll
          for (int e = 0; e < 4; ++e) {
            float x = __expf(fmaf(acc[f][s][e], rs100[s] * GETJ(rt4[f], e), -100.f));
            te += x;
            tu = fmaf(x, ubase + (float)(f * 16 + e), tu);
            acc[f][s][e] = 0.f;
          }
        ls[s] += te;
        su[s] += tu;
        sv[s] = fmaf(vb, te, sv[s]);
      }
    }
  }

  // merge 8 partials (wm x lq) per keypoint — plain sums
  __syncthreads();
#pragma unroll
  for (int s = 0; s < 4; ++s)
    red[wn * 64 + s * 16 + l15][wm * 4 + lq] = make_float4(ls[s], su[s], sv[s], 0.f);
  __syncthreads();
  if (tid < NT) {
    float L = 0.f, SU = 0.f, SV = 0.f;
#pragma unroll
    for (int i = 0; i < 8; ++i) {
      float4 q = red[tid][i];
      L += q.x; SU += q.y; SV += q.z;
    }
    partials[(size_t)(b * NKP + n0b + tid) * PSPLIT + ps] = make_float4(L, SU, SV, 0.f);
  }
}

// Fused partial-merge + coords + bilinear weights (fast path).
__global__ __launch_bounds__(256) void k_weights2(const float* __restrict__ kd,
                                                  const float* __restrict__ dd,
                                                  const float* __restrict__ ks,
                                                  const float* __restrict__ sd,
                                                  const float* __restrict__ ws_in,
                                                  const float4* __restrict__ partials,
                                                  float* __restrict__ out) {
  int wid = blockIdx.x * 4 + (threadIdx.x >> 6);
  int lane = threadIdx.x & 63;
  int b = wid >> 10, n = wid & (NKP - 1);

  float L = 0.f, SU = 0.f, SV = 0.f;
  if (lane < PSPLIT) {
    float4 q = partials[(size_t)wid * PSPLIT + lane];
    L = q.x; SU = q.y; SV = q.z;
  }
#pragma unroll
  for (int o = 1; o < 64; o <<= 1) {
    L += __shfl_xor(L, o, 64);
    SU += __shfl_xor(SU, o, 64);
    SV += __shfl_xor(SV, o, 64);
  }
  float pu = SU / L, pv = SV / L;
  if (lane == 0) {
    out[wid * 2 + 0] = pu;
    out[wid * 2 + 1] = pv;
  }

  float x = pu * (128.f / 127.f) - 0.5f;
  float y = pv * (128.f / 127.f) - 0.5f;
  float x0 = floorf(x), y0 = floorf(y);
  float wx1 = x - x0, wx0 = 1.f - wx1;
  float wy1 = y - y0, wy0 = 1.f - wy1;

  float xs[4] = {x0, x0 + 1.f, x0, x0 + 1.f};
  float ys[4] = {y0, y0, y0 + 1.f, y0 + 1.f};
  float wsc[4] = {wx0 * wy0, wx1 * wy0, wx0 * wy1, wx1 * wy1};
  float cw[4];
  int co[4];
#pragma unroll
  for (int k = 0; k < 4; ++k) {
    bool inb = (xs[k] >= 0.f) && (xs[k] < (float)WW) && (ys[k] >= 0.f) && (ys[k] < (float)HH);
    cw[k] = inb ? wsc[k] : 0.f;
    int cx = min(max((int)xs[k], 0), WW - 1);
    int cy = min(max((int)ys[k], 0), HH - 1);
    co[k] = cy * WW + cx;
  }

  const float* tgt = dd + (size_t)(2 * b + 1) * CDIM * HWPX;
  const float* srcd = kd + (size_t)(2 * b) * CDIM * NKP;
  float accd = 0.f;
  for (int c = lane; c < CDIM; c += 64) {
    const float* tc = tgt + (size_t)c * HWPX;
    float pd = cw[0] * tc[co[0]] + cw[1] * tc[co[1]] + cw[2] * tc[co[2]] + cw[3] * tc[co[3]];
    float sc = srcd[(size_t)c * NKP + n];
    accd = fmaf(sc, pd, accd);
  }
#pragma unroll
  for (int o = 32; o; o >>= 1) accd += __shfl_xor(accd, o, 64);

  if (lane == 0) {
    const float* ssc = sd + (size_t)(2 * b + 1) * HWPX;
    float psc = cw[0] * ssc[co[0]] + cw[1] * ssc[co[1]] + cw[2] * ssc[co[2]] + cw[3] * ssc[co[3]];
    float dms = accd * ws_in[WS_RS + b * NKP + n] * (1.f / (float)CDIM);
    float w = 0.5f * (dms + 1.f) * ks[(size_t)(2 * b) * NKP + n] * psc;
    out[BN * NKP * 2 + b * NKP + n] = w;
  }
}

// ======================= fallback path (round-4, passed) =======================

#define FB_NT 128
#define FB_PSPLIT 16
#define FB_PPB 1024
#define MT 256
#define KC 32
#define PT_STEPS (FB_PPB/MT)
#define CHUNKS (CDIM/KC)
#define KROW 80
#define PH_OFF 0
#define PL_OFF 20480
#define QH_OFF 40960
#define QL_OFF 51200
#define RSL_OFF 61440
#define RTL_OFF 61952
#define SM_BYTES 62976

__global__ __launch_bounds__(256) void k_rnorm_src(const float* __restrict__ kd,
                                                   float* __restrict__ ws) {
  int idx = blockIdx.x * 256 + threadIdx.x;
  int b = idx >> 10, n = idx & (NKP - 1);
  const float* p = kd + (size_t)(2 * b) * CDIM * NKP + n;
  float s = 0.f;
  for (int c = 0; c < CDIM; ++c) { float v = p[(size_t)c * NKP]; s = fmaf(v, v, s); }
  ws[WS_RS + idx] = 1.f / fmaxf(sqrtf(s), 1e-12f);
}

__global__ __launch_bounds__(256) void k_rnorm_tgt(const float* __restrict__ dd,
                                                   float* __restrict__ ws) {
  int idx = blockIdx.x * 256 + threadIdx.x;
  int b = idx >> 14, m = idx & (HWPX - 1);
  const float* p = dd + (size_t)(2 * b + 1) * CDIM * HWPX + m;
  float s = 0.f;
  for (int c = 0; c < CDIM; ++c) { float v = p[(size_t)c * HWPX]; s = fmaf(v, v, s); }
  ws[WS_RT + idx] = 1.f / fmaxf(sqrtf(s), 1e-12f);
}

__global__ __launch_bounds__(256, 2) void k_match(const float* __restrict__ kd,
                                                  const float* __restrict__ dd,
                                                  const float* __restrict__ wsp,
                                                  float4* __restrict__ partials) {
  __shared__ __align__(16) char SM[SM_BYTES];
  const int tid = threadIdx.x;
  const int w = tid >> 6, lane = tid & 63;
  const int l15 = lane & 15, lq = lane >> 4;
  const int ps = blockIdx.x, nt = blockIdx.y, b = blockIdx.z;
  const int n0b = nt * FB_NT;
  const int p0 = ps * FB_PPB;

  const float* Ag = kd + (size_t)(2 * b) * CDIM * NKP;
  const float* Bg = dd + (size_t)(2 * b + 1) * CDIM * HWPX;
  const float* rs = wsp + WS_RS + b * NKP;
  const float* rt = wsp + WS_RT + b * HWPX;

  float* rsl = (float*)(SM + RSL_OFF);
  float* rtl = (float*)(SM + RTL_OFF);
  if (tid < FB_NT) rsl[tid] = rs[n0b + tid] * 3.125f;

  const int koct = tid & 3;
  const int mq4 = (tid >> 2) * 4;

  float mx[8], ls[8], su[8], sv[8];
#pragma unroll
  for (int s = 0; s < 8; ++s) { mx[s] = -INFINITY; ls[s] = su[s] = sv[s] = 0.f; }

  const float ubase = (float)((w & 1) * 64 + lq * 4);

  for (int pt = 0; pt < PT_STEPS; ++pt) {
    const int pm0 = p0 + pt * MT;
    __syncthreads();
    rtl[tid] = rt[pm0 + tid] * 32.f;

    v4f acc[4][8];
#pragma unroll
    for (int f = 0; f < 4; ++f)
#pragma unroll
      for (int s = 0; s < 8; ++s)
#pragma unroll
        for (int e = 0; e < 4; ++e) acc[f][s][e] = 0.f;

    for (int kc = 0; kc < CHUNKS; ++kc) {
      __syncthreads();
      {
        const float* Bk = Bg + (size_t)(kc * KC + koct * 8) * HWPX + pm0 + mq4;
        float4 r[8];
#pragma unroll
        for (int rr = 0; rr < 8; ++rr) r[rr] = *(const float4*)(Bk + (size_t)rr * HWPX);
        float4 sc4 = *(const float4*)(rtl + mq4);
#pragma unroll
        for (int j = 0; j < 4; ++j) {
          const float scj = GETJ(sc4, j);
          v8h hi, lo;
#pragma unroll
          for (int rr = 0; rr < 8; ++rr) {
            float v = GETJ(r[rr], j) * scj;
            _Float16 hh = (_Float16)v;
            hi[rr] = hh;
            lo[rr] = (_Float16)(v - (float)hh);
          }
          *(v8h*)(SM + PH_OFF + (mq4 + j) * KROW + koct * 16) = hi;
          *(v8h*)(SM + PL_OFF + (mq4 + j) * KROW + koct * 16) = lo;
        }
      }
      if (tid < 128) {
        const int nq4 = (tid >> 2) * 4;
        const float* Ak = Ag + (size_t)(kc * KC + koct * 8) * NKP + n0b + nq4;
        float4 r[8];
#pragma unroll
        for (int rr = 0; rr < 8; ++rr) r[rr] = *(const float4*)(Ak + (size_t)rr * NKP);
        float4 sc4 = *(const float4*)(rsl + nq4);
#pragma unroll
        for (int j = 0; j < 4; ++j) {
          const float scj = GETJ(sc4, j);
          v8h hi, lo;
#pragma unroll
          for (int rr = 0; rr < 8; ++rr) {
            float v = GETJ(r[rr], j) * scj;
            _Float16 hh = (_Float16)v;
            hi[rr] = hh;
            lo[rr] = (_Float16)(v - (float)hh);
          }
          *(v8h*)(SM + QH_OFF + (nq4 + j) * KROW + koct * 16) = hi;
          *(v8h*)(SM + QL_OFF + (nq4 + j) * KROW + koct * 16) = lo;
        }
      }
      __syncthreads();

      v8h PHf[4], PLf[4];
#pragma unroll
      for (int f = 0; f < 4; ++f) {
        const int row = w * 64 + f * 16 + l15;
        PHf[f] = *(const v8h*)(SM + PH_OFF + row * KROW + lq * 16);
        PLf[f] = *(const v8h*)(SM + PL_OFF + row * KROW + lq * 16);
      }
#pragma unroll
      for (int s = 0; s < 8; ++s) {
        const int col = s * 16 + l15;
        v8h qh = *(const v8h*)(SM + QH_OFF + col * KROW + lq * 16);
        v8h ql = *(const v8h*)(SM + QL_OFF + col * KROW + lq * 16);
#pragma unroll
        for (int f = 0; f < 4; ++f) {
          acc[f][s] = __builtin_amdgcn_mfma_f32_16x16x32_f16(PHf[f], qh, acc[f][s], 0, 0, 0);
          acc[f][s] = __builtin_amdgcn_mfma_f32_16x16x32_f16(PLf[f], qh, acc[f][s], 0, 0, 0);
          acc[f][s] = __builtin_amdgcn_mfma_f32_16x16x32_f16(PHf[f], ql, acc[f][s], 0, 0, 0);
        }
      }
    }

    const float vb = (float)((pm0 >> 7) + (w >> 1));
#pragma unroll
    for (int s = 0; s < 8; ++s) {
      float tm = -INFINITY;
#pragma unroll
      for (int f = 0; f < 4; ++f)
#pragma unroll
        for (int e = 0; e < 4; ++e) tm = fmaxf(tm, acc[f][s][e]);
      float nm = fmaxf(mx[s], tm);
      float scf = __expf(mx[s] - nm);
      float te = 0.f, tu = 0.f;
#pragma unroll
      for (int f = 0; f < 4; ++f)
#pragma unroll
        for (int e = 0; e < 4; ++e) {
          float x = __expf(acc[f][s][e] - nm);
          te += x;
          tu = fmaf(x, ubase + (float)(f * 16 + e), tu);
        }
      ls[s] = ls[s] * scf + te;
      su[s] = su[s] * scf + tu;
      sv[s] = sv[s] * scf + vb * te;
      mx[s] = nm;
    }
  }

  __syncthreads();
  float4* red = (float4*)SM;
#pragma unroll
  for (int s = 0; s < 8; ++s)
    red[(s * 16 + l15) * 16 + w * 4 + lq] = make_float4(mx[s], ls[s], su[s], sv[s]);
  __syncthreads();
  if (tid < FB_NT) {
    float M = -INFINITY, L = 0.f, SU = 0.f, SV = 0.f;
#pragma unroll
    for (int i = 0; i < 16; ++i) {
      float4 q = red[tid * 16 + i];
      float nm2 = fmaxf(M, q.x);
      float e1 = __expf(M - nm2), e2 = __expf(q.x - nm2);
      L = L * e1 + q.y * e2; SU = SU * e1 + q.z * e2; SV = SV * e1 + q.w * e2;
      M = nm2;
    }
    partials[(size_t)(b * NKP + n0b + tid) * FB_PSPLIT + ps] = make_float4(M, L, SU, SV);
  }
}

__global__ __launch_bounds__(256) void k_coords(const float4* __restrict__ partials,
                                                float* __restrict__ out) {
  int row = blockIdx.x * 256 + threadIdx.x;
  float M = -INFINITY, L = 0.f, SU = 0.f, SV = 0.f;
  for (int i = 0; i < FB_PSPLIT; ++i) {
    float4 q = partials[(size_t)row * FB_PSPLIT + i];
    float nm = fmaxf(M, q.x);
    float e1 = __expf(M - nm), e2 = __expf(q.x - nm);
    L = L * e1 + q.y * e2; SU = SU * e1 + q.z * e2; SV = SV * e1 + q.w * e2;
    M = nm;
  }
  out[row * 2 + 0] = SU / L;
  out[row * 2 + 1] = SV / L;
}

__global__ __launch_bounds__(256) void k_weights(const float* __restrict__ kd,
                                                 const float* __restrict__ dd,
                                                 const float* __restrict__ ks,
                                                 const float* __restrict__ sd,
                                                 const float* __restrict__ ws_in,
                                                 float* __restrict__ out) {
  int wid = blockIdx.x * 4 + (threadIdx.x >> 6);
  int lane = threadIdx.x & 63;
  int b = wid >> 10, n = wid & (NKP - 1);

  float pu = out[wid * 2 + 0];
  float pv = out[wid * 2 + 1];
  float x = pu * (128.f / 127.f) - 0.5f;
  float y = pv * (128.f / 127.f) - 0.5f;
  float x0 = floorf(x), y0 = floorf(y);
  float wx1 = x - x0, wx0 = 1.f - wx1;
  float wy1 = y - y0, wy0 = 1.f - wy1;

  float xs[4] = {x0, x0 + 1.f, x0, x0 + 1.f};
  float ys[4] = {y0, y0, y0 + 1.f, y0 + 1.f};
  float wsc[4] = {wx0 * wy0, wx1 * wy0, wx0 * wy1, wx1 * wy1};
  float cw[4];
  int co[4];
#pragma unroll
  for (int k = 0; k < 4; ++k) {
    bool inb = (xs[k] >= 0.f) && (xs[k] < (float)WW) && (ys[k] >= 0.f) && (ys[k] < (float)HH);
    cw[k] = inb ? wsc[k] : 0.f;
    int cx = min(max((int)xs[k], 0), WW - 1);
    int cy = min(max((int)ys[k], 0), HH - 1);
    co[k] = cy * WW + cx;
  }

  const float* tgt = dd + (size_t)(2 * b + 1) * CDIM * HWPX;
  const float* srcd = kd + (size_t)(2 * b) * CDIM * NKP;
  float accd = 0.f;
  for (int c = lane; c < CDIM; c += 64) {
    const float* tc = tgt + (size_t)c * HWPX;
    float pd = cw[0] * tc[co[0]] + cw[1] * tc[co[1]] + cw[2] * tc[co[2]] + cw[3] * tc[co[3]];
    float sc = srcd[(size_t)c * NKP + n];
    accd = fmaf(sc, pd, accd);
  }
#pragma unroll
  for (int o = 32; o; o >>= 1) accd += __shfl_xor(accd, o, 64);

  if (lane == 0) {
    const float* ssc = sd + (size_t)(2 * b + 1) * HWPX;
    float psc = cw[0] * ssc[co[0]] + cw[1] * ssc[co[1]] + cw[2] * ssc[co[2]] + cw[3] * ssc[co[3]];
    float dms = accd * ws_in[WS_RS + b * NKP + n] * (1.f / (float)CDIM);
    float w = 0.5f * (dms + 1.f) * ks[(size_t)(2 * b) * NKP + n] * psc;
    out[BN * NKP * 2 + b * NKP + n] = w;
  }
}

extern "C" void kernel_launch(void* const* d_in, const int* in_sizes, int n_in,
                              void* d_out, int out_size, void* d_ws, size_t ws_size,
                              hipStream_t stream) {
  const float* ks = (const float*)d_in[0];
  const float* kd = (const float*)d_in[1];
  const float* sd = (const float*)d_in[2];
  const float* dd = (const float*)d_in[3];
  float* out = (float*)d_out;
  float* ws = (float*)d_ws;

  if (ws_size >= (size_t)WS_NEED) {
    char* pq = (char*)d_ws + WS_PQ_B;
    char* pp = (char*)d_ws + WS_PP_B;
    hipLaunchKernelGGL(k_prep, dim3(272), dim3(256), 0, stream, kd, dd, ws, pq, pp);
    hipLaunchKernelGGL(k_match3, dim3(1024), dim3(256), 0, stream,
                       pp, pq, ws, (float4*)(ws + WS_PART));
    hipLaunchKernelGGL(k_weights2, dim3(BN * NKP / 4), dim3(256), 0, stream,
                       kd, dd, ks, sd, ws, (const float4*)(ws + WS_PART), out);
  } else {
    hipLaunchKernelGGL(k_rnorm_src, dim3(BN * NKP / 256), dim3(256), 0, stream, kd, ws);
    hipLaunchKernelGGL(k_rnorm_tgt, dim3(BN * HWPX / 256), dim3(256), 0, stream, dd, ws);
    hipLaunchKernelGGL(k_match, dim3(FB_PSPLIT, NKP / FB_NT, BN), dim3(256), 0, stream,
                       kd, dd, ws, (float4*)(ws + WS_PART));
    hipLaunchKernelGGL(k_coords, dim3(BN * NKP / 256), dim3(256), 0, stream,
                       (const float4*)(ws + WS_PART), out);
    hipLaunchKernelGGL(k_weights, dim3(BN * NKP / 4), dim3(256), 0, stream,
                       kd, dd, ks, sd, ws, out);
  }
}

// Round 14
// 110.599 us; speedup vs baseline: 1.7976x; 1.7976x over previous
//
#include <hip/hip_runtime.h>
#include <math.h>

#define BN 4
#define CDIM 256
#define NKP 1024
#define HH 128
#define WW 128
#define HWPX (HH*WW)

#define PSPLIT 32
#define PPB 512
#define NT 128

// ---- workspace layout ----
#define WS_RS 0
#define WS_RT (WS_RS + BN*NKP)
#define WS_PART (WS_RT + BN*HWPX)          // float4[BN*NKP*PSPLIT] = 2 MB
#define WS_PQ_B 2375680u                   // [b][kc][64 frag]x1024B = 4 MB region
#define WS_PP_B 6569984u                   // [b][kc][1024 frag]x1024B (HI ONLY) = 32 MB
#define WS_NEED 40124416u

typedef __attribute__((ext_vector_type(8)))  _Float16 v8h;
typedef __attribute__((ext_vector_type(4)))  float v4f;

#define GETJ(v, j) ((j) == 0 ? (v).x : (j) == 1 ? (v).y : (j) == 2 ? (v).z : (v).w)

// ======================= fast path =======================

// Fused prep: blocks 0..255: P (dd) -> f16 HI plane. Blocks 256..271: Q (kd)
// -> f16 HI plane (1-term scheme; logit err ~5e-3 vs 0.5 bf16 output floor).
// Fragment block = 1024 B: [4 ko][16 col][16 B]; frag index = col>>4.
__global__ __launch_bounds__(256) void k_prep(const float* __restrict__ kd,
                                              const float* __restrict__ dd,
                                              float* __restrict__ wsf,
                                              char* __restrict__ pq,
                                              char* __restrict__ pp) {
  if (blockIdx.x < 256) {
    int id = blockIdx.x;                 // 256 = b*64 + mb
    int b = id >> 6;
    int m = (id & 63) * 256 + threadIdx.x;
    const float* p = dd + (size_t)(2 * b + 1) * CDIM * HWPX + m;
    char* mb = pp + (size_t)b * 8388608 + (m >> 4) * 1024 + (m & 15) * 16;
    float s = 0.f;
#pragma unroll
    for (int kc = 0; kc < 8; ++kc) {
#pragma unroll
      for (int ko = 0; ko < 4; ++ko) {
        v8h hi;
#pragma unroll
        for (int j = 0; j < 8; ++j) {
          float v = p[(size_t)(kc * 32 + ko * 8 + j) * HWPX];
          s = fmaf(v, v, s);
          hi[j] = (_Float16)(v * 32.f);
        }
        *(v8h*)(mb + (size_t)kc * 1048576 + ko * 256) = hi;
      }
    }
    wsf[WS_RT + b * HWPX + m] = 1.f / fmaxf(sqrtf(s), 1e-12f);
  } else {
    int id = blockIdx.x - 256;           // 16 = b*4 + nb
    int b = id >> 2;
    int n = (id & 3) * 256 + threadIdx.x;
    const float* p = kd + (size_t)(2 * b) * CDIM * NKP + n;
    char* qb = pq + (size_t)b * 1048576 + (n >> 4) * 1024 + (n & 15) * 16;
    float s = 0.f;
#pragma unroll
    for (int kc = 0; kc < 8; ++kc) {
#pragma unroll
      for (int ko = 0; ko < 4; ++ko) {
        v8h hi;
#pragma unroll
        for (int j = 0; j < 8; ++j) {
          float v = p[(size_t)(kc * 32 + ko * 8 + j) * NKP];
          s = fmaf(v, v, s);
          hi[j] = (_Float16)(v * 32.f);
        }
        *(v8h*)(qb + (size_t)kc * 131072 + ko * 256) = hi;
      }
    }
    wsf[WS_RS + b * NKP + n] = 1.f / fmaxf(sqrtf(s), 1e-12f);
  }
}

// Zero-LDS (merge-only) fused MFMA GEMM + fixed-shift softmax, 1-term f16.
// PSPLIT=32 -> grid 1024; launch_bounds(256,3) -> ~170 VGPR cap (NO spill;
// r13's (256,4)=128 cap spilled acc to scratch). A/B double-buffered frags.
#define LOADT(ph, qh, t) do {                                                  \
  const int pt_ = (t) >> 3, kc_ = (t) & 7;                                     \
  const char* Pb_ = ppb + (size_t)kc_ * 1048576 + (size_t)(frp + pt_ * 8) * 1024; \
  const char* Qb_ = pqb + (size_t)kc_ * 131072 + (size_t)frq * 1024;           \
  _Pragma("unroll")                                                            \
  for (int f_ = 0; f_ < 4; ++f_) {                                             \
    ph[f_] = *(const v8h*)(Pb_ + f_ * 1024 + lane16);                          \
    qh[f_] = *(const v8h*)(Qb_ + f_ * 1024 + lane16);                          \
  }                                                                            \
} while (0)

#define MFMAT(ph, qh)                                                          \
  __builtin_amdgcn_s_setprio(1);                                               \
  _Pragma("unroll")                                                            \
  for (int s_ = 0; s_ < 4; ++s_) {                                             \
    _Pragma("unroll")                                                          \
    for (int f_ = 0; f_ < 4; ++f_) {                                           \
      acc[f_][s_] = __builtin_amdgcn_mfma_f32_16x16x32_f16(ph[f_], qh[s_], acc[f_][s_], 0, 0, 0); \
    }                                                                          \
  }                                                                            \
  __builtin_amdgcn_s_setprio(0);

__global__ __launch_bounds__(256, 3) void k_match3(const char* __restrict__ pp,
                                                   const char* __restrict__ pq,
                                                   const float* __restrict__ wsf,
                                                   float4* __restrict__ partials) {
  __shared__ float4 red[NT][8];   // 16 KB merge buffer only
  const int tid = threadIdx.x;
  const int w = tid >> 6, lane = tid & 63;
  const int l15 = lane & 15, lq = lane >> 4;
  const int wm = w & 1, wn = w >> 1;

  // XCD-chunked grid: XCD x owns b = x>>1 and a contiguous 16-ps range.
  const int raw = blockIdx.x;
  const int fid = (raw & 7) * 128 + (raw >> 3);
  const int b = fid >> 8, ps = (fid >> 3) & 31, nt = fid & 7;
  const int n0b = nt * NT;

  const char* ppb = pp + (size_t)b * 8388608;
  const char* pqb = pq + (size_t)b * 1048576;
  const float* rtp = wsf + WS_RT + b * HWPX + ps * PPB;
  const float* rsp = wsf + WS_RS + b * NKP;

  const int frp = ps * 32 + wm * 4;
  const int frq = nt * 8 + wn * 4;
  const unsigned lane16 = (unsigned)lane * 16;

  float rs100[4];
#pragma unroll
  for (int s = 0; s < 4; ++s)
    rs100[s] = rsp[n0b + wn * 64 + s * 16 + l15] * (100.f / 1024.f);

  float ls[4], su[4], sv[4];
#pragma unroll
  for (int s = 0; s < 4; ++s) { ls[s] = su[s] = sv[s] = 0.f; }

  v4f acc[4][4];
#pragma unroll
  for (int f = 0; f < 4; ++f)
#pragma unroll
    for (int s = 0; s < 4; ++s)
#pragma unroll
      for (int e = 0; e < 4; ++e) acc[f][s][e] = 0.f;

  const float ubase = (float)(wm * 64 + lq * 4);
  const float vbase = (float)(ps * 4);

  v8h phA[4], qhA[4], phB[4], qhB[4];
  LOADT(phA, qhA, 0);

  for (int t2 = 0; t2 < 32; t2 += 2) {
    LOADT(phB, qhB, t2 + 1);
    MFMAT(phA, qhA);
    if (t2 + 2 < 32) LOADT(phA, qhA, t2 + 2);
    MFMAT(phB, qhB);

    if (((t2 + 1) & 7) == 7) {           // K complete for this 128-px tile
      const int pt = t2 >> 3;
      const float vb = vbase + (float)pt;
      float4 rt4[4];
#pragma unroll
      for (int f = 0; f < 4; ++f)
        rt4[f] = *(const float4*)(rtp + pt * 128 + wm * 64 + f * 16 + lq * 4);
#pragma unroll
      for (int s = 0; s < 4; ++s) {
        float te = 0.f, tu = 0.f;
#pragma unroll
        for (int f = 0; f < 4; ++f)
#pragma unroll
          for (int e = 0; e < 4; ++e) {
            float x = __expf(fmaf(acc[f][s][e], rs100[s] * GETJ(rt4[f], e), -100.f));
            te += x;
            tu = fmaf(x, ubase + (float)(f * 16 + e), tu);
            acc[f][s][e] = 0.f;
          }
        ls[s] += te;
        su[s] += tu;
        sv[s] = fmaf(vb, te, sv[s]);
      }
    }
  }

  // merge 8 partials (wm x lq) per keypoint — plain sums
  __syncthreads();
#pragma unroll
  for (int s = 0; s < 4; ++s)
    red[wn * 64 + s * 16 + l15][wm * 4 + lq] = make_float4(ls[s], su[s], sv[s], 0.f);
  __syncthreads();
  if (tid < NT) {
    float L = 0.f, SU = 0.f, SV = 0.f;
#pragma unroll
    for (int i = 0; i < 8; ++i) {
      float4 q = red[tid][i];
      L += q.x; SU += q.y; SV += q.z;
    }
    partials[(size_t)(b * NKP + n0b + tid) * PSPLIT + ps] = make_float4(L, SU, SV, 0.f);
  }
}

// Fused partial-merge + coords + bilinear weights (fast path).
__global__ __launch_bounds__(256) void k_weights2(const float* __restrict__ kd,
                                                  const float* __restrict__ dd,
                                                  const float* __restrict__ ks,
                                                  const float* __restrict__ sd,
                                                  const float* __restrict__ ws_in,
                                                  const float4* __restrict__ partials,
                                                  float* __restrict__ out) {
  int wid = blockIdx.x * 4 + (threadIdx.x >> 6);
  int lane = threadIdx.x & 63;
  int b = wid >> 10, n = wid & (NKP - 1);

  float L = 0.f, SU = 0.f, SV = 0.f;
  if (lane < PSPLIT) {
    float4 q = partials[(size_t)wid * PSPLIT + lane];
    L = q.x; SU = q.y; SV = q.z;
  }
#pragma unroll
  for (int o = 1; o < 64; o <<= 1) {
    L += __shfl_xor(L, o, 64);
    SU += __shfl_xor(SU, o, 64);
    SV += __shfl_xor(SV, o, 64);
  }
  float pu = SU / L, pv = SV / L;
  if (lane == 0) {
    out[wid * 2 + 0] = pu;
    out[wid * 2 + 1] = pv;
  }

  float x = pu * (128.f / 127.f) - 0.5f;
  float y = pv * (128.f / 127.f) - 0.5f;
  float x0 = floorf(x), y0 = floorf(y);
  float wx1 = x - x0, wx0 = 1.f - wx1;
  float wy1 = y - y0, wy0 = 1.f - wy1;

  float xs[4] = {x0, x0 + 1.f, x0, x0 + 1.f};
  float ys[4] = {y0, y0, y0 + 1.f, y0 + 1.f};
  float wsc[4] = {wx0 * wy0, wx1 * wy0, wx0 * wy1, wx1 * wy1};
  float cw[4];
  int co[4];
#pragma unroll
  for (int k = 0; k < 4; ++k) {
    bool inb = (xs[k] >= 0.f) && (xs[k] < (float)WW) && (ys[k] >= 0.f) && (ys[k] < (float)HH);
    cw[k] = inb ? wsc[k] : 0.f;
    int cx = min(max((int)xs[k], 0), WW - 1);
    int cy = min(max((int)ys[k], 0), HH - 1);
    co[k] = cy * WW + cx;
  }

  const float* tgt = dd + (size_t)(2 * b + 1) * CDIM * HWPX;
  const float* srcd = kd + (size_t)(2 * b) * CDIM * NKP;
  float accd = 0.f;
  for (int c = lane; c < CDIM; c += 64) {
    const float* tc = tgt + (size_t)c * HWPX;
    float pd = cw[0] * tc[co[0]] + cw[1] * tc[co[1]] + cw[2] * tc[co[2]] + cw[3] * tc[co[3]];
    float sc = srcd[(size_t)c * NKP + n];
    accd = fmaf(sc, pd, accd);
  }
#pragma unroll
  for (int o = 32; o; o >>= 1) accd += __shfl_xor(accd, o, 64);

  if (lane == 0) {
    const float* ssc = sd + (size_t)(2 * b + 1) * HWPX;
    float psc = cw[0] * ssc[co[0]] + cw[1] * ssc[co[1]] + cw[2] * ssc[co[2]] + cw[3] * ssc[co[3]];
    float dms = accd * ws_in[WS_RS + b * NKP + n] * (1.f / (float)CDIM);
    float w = 0.5f * (dms + 1.f) * ks[(size_t)(2 * b) * NKP + n] * psc;
    out[BN * NKP * 2 + b * NKP + n] = w;
  }
}

// ======================= fallback path (round-4, passed) =======================

#define FB_NT 128
#define FB_PSPLIT 16
#define FB_PPB 1024
#define MT 256
#define KC 32
#define PT_STEPS (FB_PPB/MT)
#define CHUNKS (CDIM/KC)
#define KROW 80
#define PH_OFF 0
#define PL_OFF 20480
#define QH_OFF 40960
#define QL_OFF 51200
#define RSL_OFF 61440
#define RTL_OFF 61952
#define SM_BYTES 62976

__global__ __launch_bounds__(256) void k_rnorm_src(const float* __restrict__ kd,
                                                   float* __restrict__ ws) {
  int idx = blockIdx.x * 256 + threadIdx.x;
  int b = idx >> 10, n = idx & (NKP - 1);
  const float* p = kd + (size_t)(2 * b) * CDIM * NKP + n;
  float s = 0.f;
  for (int c = 0; c < CDIM; ++c) { float v = p[(size_t)c * NKP]; s = fmaf(v, v, s); }
  ws[WS_RS + idx] = 1.f / fmaxf(sqrtf(s), 1e-12f);
}

__global__ __launch_bounds__(256) void k_rnorm_tgt(const float* __restrict__ dd,
                                                   float* __restrict__ ws) {
  int idx = blockIdx.x * 256 + threadIdx.x;
  int b = idx >> 14, m = idx & (HWPX - 1);
  const float* p = dd + (size_t)(2 * b + 1) * CDIM * HWPX + m;
  float s = 0.f;
  for (int c = 0; c < CDIM; ++c) { float v = p[(size_t)c * HWPX]; s = fmaf(v, v, s); }
  ws[WS_RT + idx] = 1.f / fmaxf(sqrtf(s), 1e-12f);
}

__global__ __launch_bounds__(256, 2) void k_match(const float* __restrict__ kd,
                                                  const float* __restrict__ dd,
                                                  const float* __restrict__ wsp,
                                                  float4* __restrict__ partials) {
  __shared__ __align__(16) char SM[SM_BYTES];
  const int tid = threadIdx.x;
  const int w = tid >> 6, lane = tid & 63;
  const int l15 = lane & 15, lq = lane >> 4;
  const int ps = blockIdx.x, nt = blockIdx.y, b = blockIdx.z;
  const int n0b = nt * FB_NT;
  const int p0 = ps * FB_PPB;

  const float* Ag = kd + (size_t)(2 * b) * CDIM * NKP;
  const float* Bg = dd + (size_t)(2 * b + 1) * CDIM * HWPX;
  const float* rs = wsp + WS_RS + b * NKP;
  const float* rt = wsp + WS_RT + b * HWPX;

  float* rsl = (float*)(SM + RSL_OFF);
  float* rtl = (float*)(SM + RTL_OFF);
  if (tid < FB_NT) rsl[tid] = rs[n0b + tid] * 3.125f;

  const int koct = tid & 3;
  const int mq4 = (tid >> 2) * 4;

  float mx[8], ls[8], su[8], sv[8];
#pragma unroll
  for (int s = 0; s < 8; ++s) { mx[s] = -INFINITY; ls[s] = su[s] = sv[s] = 0.f; }

  const float ubase = (float)((w & 1) * 64 + lq * 4);

  for (int pt = 0; pt < PT_STEPS; ++pt) {
    const int pm0 = p0 + pt * MT;
    __syncthreads();
    rtl[tid] = rt[pm0 + tid] * 32.f;

    v4f acc[4][8];
#pragma unroll
    for (int f = 0; f < 4; ++f)
#pragma unroll
      for (int s = 0; s < 8; ++s)
#pragma unroll
        for (int e = 0; e < 4; ++e) acc[f][s][e] = 0.f;

    for (int kc = 0; kc < CHUNKS; ++kc) {
      __syncthreads();
      {
        const float* Bk = Bg + (size_t)(kc * KC + koct * 8) * HWPX + pm0 + mq4;
        float4 r[8];
#pragma unroll
        for (int rr = 0; rr < 8; ++rr) r[rr] = *(const float4*)(Bk + (size_t)rr * HWPX);
        float4 sc4 = *(const float4*)(rtl + mq4);
#pragma unroll
        for (int j = 0; j < 4; ++j) {
          const float scj = GETJ(sc4, j);
          v8h hi, lo;
#pragma unroll
          for (int rr = 0; rr < 8; ++rr) {
            float v = GETJ(r[rr], j) * scj;
            _Float16 hh = (_Float16)v;
            hi[rr] = hh;
            lo[rr] = (_Float16)(v - (float)hh);
          }
          *(v8h*)(SM + PH_OFF + (mq4 + j) * KROW + koct * 16) = hi;
          *(v8h*)(SM + PL_OFF + (mq4 + j) * KROW + koct * 16) = lo;
        }
      }
      if (tid < 128) {
        const int nq4 = (tid >> 2) * 4;
        const float* Ak = Ag + (size_t)(kc * KC + koct * 8) * NKP + n0b + nq4;
        float4 r[8];
#pragma unroll
        for (int rr = 0; rr < 8; ++rr) r[rr] = *(const float4*)(Ak + (size_t)rr * NKP);
        float4 sc4 = *(const float4*)(rsl + nq4);
#pragma unroll
        for (int j = 0; j < 4; ++j) {
          const float scj = GETJ(sc4, j);
          v8h hi, lo;
#pragma unroll
          for (int rr = 0; rr < 8; ++rr) {
            float v = GETJ(r[rr], j) * scj;
            _Float16 hh = (_Float16)v;
            hi[rr] = hh;
            lo[rr] = (_Float16)(v - (float)hh);
          }
          *(v8h*)(SM + QH_OFF + (nq4 + j) * KROW + koct * 16) = hi;
          *(v8h*)(SM + QL_OFF + (nq4 + j) * KROW + koct * 16) = lo;
        }
      }
      __syncthreads();

      v8h PHf[4], PLf[4];
#pragma unroll
      for (int f = 0; f < 4; ++f) {
        const int row = w * 64 + f * 16 + l15;
        PHf[f] = *(const v8h*)(SM + PH_OFF + row * KROW + lq * 16);
        PLf[f] = *(const v8h*)(SM + PL_OFF + row * KROW + lq * 16);
      }
#pragma unroll
      for (int s = 0; s < 8; ++s) {
        const int col = s * 16 + l15;
        v8h qh = *(const v8h*)(SM + QH_OFF + col * KROW + lq * 16);
        v8h ql = *(const v8h*)(SM + QL_OFF + col * KROW + lq * 16);
#pragma unroll
        for (int f = 0; f < 4; ++f) {
          acc[f][s] = __builtin_amdgcn_mfma_f32_16x16x32_f16(PHf[f], qh, acc[f][s], 0, 0, 0);
          acc[f][s] = __builtin_amdgcn_mfma_f32_16x16x32_f16(PLf[f], qh, acc[f][s], 0, 0, 0);
          acc[f][s] = __builtin_amdgcn_mfma_f32_16x16x32_f16(PHf[f], ql, acc[f][s], 0, 0, 0);
        }
      }
    }

    const float vb = (float)((pm0 >> 7) + (w >> 1));
#pragma unroll
    for (int s = 0; s < 8; ++s) {
      float tm = -INFINITY;
#pragma unroll
      for (int f = 0; f < 4; ++f)
#pragma unroll
        for (int e = 0; e < 4; ++e) tm = fmaxf(tm, acc[f][s][e]);
      float nm = fmaxf(mx[s], tm);
      float scf = __expf(mx[s] - nm);
      float te = 0.f, tu = 0.f;
#pragma unroll
      for (int f = 0; f < 4; ++f)
#pragma unroll
        for (int e = 0; e < 4; ++e) {
          float x = __expf(acc[f][s][e] - nm);
          te += x;
          tu = fmaf(x, ubase + (float)(f * 16 + e), tu);
        }
      ls[s] = ls[s] * scf + te;
      su[s] = su[s] * scf + tu;
      sv[s] = sv[s] * scf + vb * te;
      mx[s] = nm;
    }
  }

  __syncthreads();
  float4* red = (float4*)SM;
#pragma unroll
  for (int s = 0; s < 8; ++s)
    red[(s * 16 + l15) * 16 + w * 4 + lq] = make_float4(mx[s], ls[s], su[s], sv[s]);
  __syncthreads();
  if (tid < FB_NT) {
    float M = -INFINITY, L = 0.f, SU = 0.f, SV = 0.f;
#pragma unroll
    for (int i = 0; i < 16; ++i) {
      float4 q = red[tid * 16 + i];
      float nm2 = fmaxf(M, q.x);
      float e1 = __expf(M - nm2), e2 = __expf(q.x - nm2);
      L = L * e1 + q.y * e2; SU = SU * e1 + q.z * e2; SV = SV * e1 + q.w * e2;
      M = nm2;
    }
    partials[(size_t)(b * NKP + n0b + tid) * FB_PSPLIT + ps] = make_float4(M, L, SU, SV);
  }
}

__global__ __launch_bounds__(256) void k_coords(const float4* __restrict__ partials,
                                                float* __restrict__ out) {
  int row = blockIdx.x * 256 + threadIdx.x;
  float M = -INFINITY, L = 0.f, SU = 0.f, SV = 0.f;
  for (int i = 0; i < FB_PSPLIT; ++i) {
    float4 q = partials[(size_t)row * FB_PSPLIT + i];
    float nm = fmaxf(M, q.x);
    float e1 = __expf(M - nm), e2 = __expf(q.x - nm);
    L = L * e1 + q.y * e2; SU = SU * e1 + q.z * e2; SV = SV * e1 + q.w * e2;
    M = nm;
  }
  out[row * 2 + 0] = SU / L;
  out[row * 2 + 1] = SV / L;
}

__global__ __launch_bounds__(256) void k_weights(const float* __restrict__ kd,
                                                 const float* __restrict__ dd,
                                                 const float* __restrict__ ks,
                                                 const float* __restrict__ sd,
                                                 const float* __restrict__ ws_in,
                                                 float* __restrict__ out) {
  int wid = blockIdx.x * 4 + (threadIdx.x >> 6);
  int lane = threadIdx.x & 63;
  int b = wid >> 10, n = wid & (NKP - 1);

  float pu = out[wid * 2 + 0];
  float pv = out[wid * 2 + 1];
  float x = pu * (128.f / 127.f) - 0.5f;
  float y = pv * (128.f / 127.f) - 0.5f;
  float x0 = floorf(x), y0 = floorf(y);
  float wx1 = x - x0, wx0 = 1.f - wx1;
  float wy1 = y - y0, wy0 = 1.f - wy1;

  float xs[4] = {x0, x0 + 1.f, x0, x0 + 1.f};
  float ys[4] = {y0, y0, y0 + 1.f, y0 + 1.f};
  float wsc[4] = {wx0 * wy0, wx1 * wy0, wx0 * wy1, wx1 * wy1};
  float cw[4];
  int co[4];
#pragma unroll
  for (int k = 0; k < 4; ++k) {
    bool inb = (xs[k] >= 0.f) && (xs[k] < (float)WW) && (ys[k] >= 0.f) && (ys[k] < (float)HH);
    cw[k] = inb ? wsc[k] : 0.f;
    int cx = min(max((int)xs[k], 0), WW - 1);
    int cy = min(max((int)ys[k], 0), HH - 1);
    co[k] = cy * WW + cx;
  }

  const float* tgt = dd + (size_t)(2 * b + 1) * CDIM * HWPX;
  const float* srcd = kd + (size_t)(2 * b) * CDIM * NKP;
  float accd = 0.f;
  for (int c = lane; c < CDIM; c += 64) {
    const float* tc = tgt + (size_t)c * HWPX;
    float pd = cw[0] * tc[co[0]] + cw[1] * tc[co[1]] + cw[2] * tc[co[2]] + cw[3] * tc[co[3]];
    float sc = srcd[(size_t)c * NKP + n];
    accd = fmaf(sc, pd, accd);
  }
#pragma unroll
  for (int o = 32; o; o >>= 1) accd += __shfl_xor(accd, o, 64);

  if (lane == 0) {
    const float* ssc = sd + (size_t)(2 * b + 1) * HWPX;
    float psc = cw[0] * ssc[co[0]] + cw[1] * ssc[co[1]] + cw[2] * ssc[co[2]] + cw[3] * ssc[co[3]];
    float dms = accd * ws_in[WS_RS + b * NKP + n] * (1.f / (float)CDIM);
    float w = 0.5f * (dms + 1.f) * ks[(size_t)(2 * b) * NKP + n] * psc;
    out[BN * NKP * 2 + b * NKP + n] = w;
  }
}

extern "C" void kernel_launch(void* const* d_in, const int* in_sizes, int n_in,
                              void* d_out, int out_size, void* d_ws, size_t ws_size,
                              hipStream_t stream) {
  const float* ks = (const float*)d_in[0];
  const float* kd = (const float*)d_in[1];
  const float* sd = (const float*)d_in[2];
  const float* dd = (const float*)d_in[3];
  float* out = (float*)d_out;
  float* ws = (float*)d_ws;

  if (ws_size >= (size_t)WS_NEED) {
    char* pq = (char*)d_ws + WS_PQ_B;
    char* pp = (char*)d_ws + WS_PP_B;
    hipLaunchKernelGGL(k_prep, dim3(272), dim3(256), 0, stream, kd, dd, ws, pq, pp);
    hipLaunchKernelGGL(k_match3, dim3(1024), dim3(256), 0, stream,
                       pp, pq, ws, (float4*)(ws + WS_PART));
    hipLaunchKernelGGL(k_weights2, dim3(BN * NKP / 4), dim3(256), 0, stream,
                       kd, dd, ks, sd, ws, (const float4*)(ws + WS_PART), out);
  } else {
    hipLaunchKernelGGL(k_rnorm_src, dim3(BN * NKP / 256), dim3(256), 0, stream, kd, ws);
    hipLaunchKernelGGL(k_rnorm_tgt, dim3(BN * HWPX / 256), dim3(256), 0, stream, dd, ws);
    hipLaunchKernelGGL(k_match, dim3(FB_PSPLIT, NKP / FB_NT, BN), dim3(256), 0, stream,
                       kd, dd, ws, (float4*)(ws + WS_PART));
    hipLaunchKernelGGL(k_coords, dim3(BN * NKP / 256), dim3(256), 0, stream,
                       (const float4*)(ws + WS_PART), out);
    hipLaunchKernelGGL(k_weights, dim3(BN * NKP / 4), dim3(256), 0, stream,
                       kd, dd, ks, sd, ws, out);
  }
}

// Round 15
// 95.910 us; speedup vs baseline: 2.0730x; 1.1532x over previous
//
#include <hip/hip_runtime.h>
#include <math.h>

#define BN 4
#define CDIM 256
#define NKP 1024
#define HH 128
#define WW 128
#define HWPX (HH*WW)

#define PSPLIT 16
#define PPB 1024
#define NT 128

// ---- workspace layout ----
#define WS_RS 0
#define WS_RT (WS_RS + BN*NKP)
#define WS_PART (WS_RT + BN*HWPX)          // float4[BN*NKP*PSPLIT]
#define WS_PQ_B 1327104u                   // [b][kc][64 frag]x1024B = 4 MB region
#define WS_PP_B 5521408u                   // [b][kc][1024 frag]x1024B (HI ONLY) = 32 MB
#define WS_NEED 39075840u

typedef __attribute__((ext_vector_type(8)))  _Float16 v8h;
typedef __attribute__((ext_vector_type(4)))  float v4f;

#define GETJ(v, j) ((j) == 0 ? (v).x : (j) == 1 ? (v).y : (j) == 2 ? (v).z : (v).w)

// ======================= fast path =======================

// Fused prep, 2-threads-per-element for 2x occupancy (r12's 272-block version
// ran at ~1 block/CU, latency-bound). Even/odd lanes split channels into
// halves (4 kc-planes each); norm combined via shfl_xor(1) within the pair.
// Blocks 0..511: P (dd) -> f16 HI. Blocks 512..543: Q (kd) -> f16 HI.
// Fragment block = 1024 B: [4 ko][16 col][16 B]; frag index = col>>4.
__global__ __launch_bounds__(256) void k_prep(const float* __restrict__ kd,
                                              const float* __restrict__ dd,
                                              float* __restrict__ wsf,
                                              char* __restrict__ pq,
                                              char* __restrict__ pp) {
  const int tid = threadIdx.x;
  const int half = tid & 1;
  const int kc0 = half * 4;
  if (blockIdx.x < 512) {
    int id = blockIdx.x;                 // 512 = b*128 + mb
    int b = id >> 7;
    int m = (id & 127) * 128 + (tid >> 1);
    const float* p = dd + (size_t)(2 * b + 1) * CDIM * HWPX + m;
    char* mb = pp + (size_t)b * 8388608 + (m >> 4) * 1024 + (m & 15) * 16;
    float s = 0.f;
#pragma unroll
    for (int kc = 0; kc < 4; ++kc) {
#pragma unroll
      for (int ko = 0; ko < 4; ++ko) {
        v8h hi;
#pragma unroll
        for (int j = 0; j < 8; ++j) {
          float v = p[(size_t)((kc0 + kc) * 32 + ko * 8 + j) * HWPX];
          s = fmaf(v, v, s);
          hi[j] = (_Float16)(v * 32.f);
        }
        *(v8h*)(mb + (size_t)(kc0 + kc) * 1048576 + ko * 256) = hi;
      }
    }
    s += __shfl_xor(s, 1, 64);
    if (half == 0) wsf[WS_RT + b * HWPX + m] = 1.f / fmaxf(sqrtf(s), 1e-12f);
  } else {
    int id = blockIdx.x - 512;           // 32 = b*8 + nb
    int b = id >> 3;
    int n = (id & 7) * 128 + (tid >> 1);
    const float* p = kd + (size_t)(2 * b) * CDIM * NKP + n;
    char* qb = pq + (size_t)b * 1048576 + (n >> 4) * 1024 + (n & 15) * 16;
    float s = 0.f;
#pragma unroll
    for (int kc = 0; kc < 4; ++kc) {
#pragma unroll
      for (int ko = 0; ko < 4; ++ko) {
        v8h hi;
#pragma unroll
        for (int j = 0; j < 8; ++j) {
          float v = p[(size_t)((kc0 + kc) * 32 + ko * 8 + j) * NKP];
          s = fmaf(v, v, s);
          hi[j] = (_Float16)(v * 32.f);
        }
        *(v8h*)(qb + (size_t)(kc0 + kc) * 131072 + ko * 256) = hi;
      }
    }
    s += __shfl_xor(s, 1, 64);
    if (half == 0) wsf[WS_RS + b * NKP + n] = 1.f / fmaxf(sqrtf(s), 1e-12f);
  }
}

// Zero-barrier-loop fused MFMA GEMM + fixed-shift softmax, 1-term f16
// (exact r12 config, measured 94.8 us total): NT=128, Qh plane wholly in
// 64 KB LDS, grid 512 = exactly 2 blocks/CU, A/B double-buffered fragments.
#define LOADT(ph, qh, t) do {                                                  \
  const int pt_ = (t) >> 3, kc_ = (t) & 7;                                     \
  const char* Pb_ = ppb + (size_t)kc_ * 1048576 + (size_t)(frp + pt_ * 8) * 1024; \
  const char* Qs_ = QSM + kc_ * 8192 + wn * 4096;                              \
  _Pragma("unroll")                                                            \
  for (int f_ = 0; f_ < 4; ++f_) {                                             \
    ph[f_] = *(const v8h*)(Pb_ + f_ * 1024 + lane16);                          \
    qh[f_] = *(const v8h*)(Qs_ + f_ * 1024 + lane16);                          \
  }                                                                            \
} while (0)

#define MFMAT(ph, qh)                                                          \
  __builtin_amdgcn_s_setprio(1);                                               \
  _Pragma("unroll")                                                            \
  for (int s_ = 0; s_ < 4; ++s_) {                                             \
    _Pragma("unroll")                                                          \
    for (int f_ = 0; f_ < 4; ++f_) {                                           \
      acc[f_][s_] = __builtin_amdgcn_mfma_f32_16x16x32_f16(ph[f_], qh[s_], acc[f_][s_], 0, 0, 0); \
    }                                                                          \
  }                                                                            \
  __builtin_amdgcn_s_setprio(0);

__global__ __launch_bounds__(256, 2) void k_match3(const char* __restrict__ pp,
                                                   const char* __restrict__ pq,
                                                   const float* __restrict__ wsf,
                                                   float4* __restrict__ partials) {
  __shared__ __align__(16) char QSM[65536];
  const int tid = threadIdx.x;
  const int w = tid >> 6, lane = tid & 63;
  const int l15 = lane & 15, lq = lane >> 4;
  const int wm = w & 1, wn = w >> 1;

  // XCD-chunked grid: fid = b*128 + ps*8 + nt; XCD x owns b = x>>1, 8 ps values.
  const int raw = blockIdx.x;
  const int fid = (raw & 7) * 64 + (raw >> 3);
  const int b = fid >> 7, ps = (fid >> 3) & 15, nt = fid & 7;
  const int n0b = nt * NT;

  const char* ppb = pp + (size_t)b * 8388608;
  const char* pqb = pq + (size_t)b * 1048576;
  const float* rtp = wsf + WS_RT + b * HWPX + ps * PPB;
  const float* rsp = wsf + WS_RS + b * NKP;

  const int frp = ps * 64 + wm * 4;
  const unsigned lane16 = (unsigned)lane * 16;

  // ---- stage Qh plane (block's 128 n, all 8 kc) into LDS: 64 KB ----
#pragma unroll
  for (int j = 0; j < 16; ++j) {
    int off = j * 4096 + tid * 16;
    int kc = off >> 13, rem = off & 8191;   // rem = f*1024 + l16, f<8
    *(float4*)(QSM + off) =
        *(const float4*)(pqb + (size_t)kc * 131072 + (size_t)(nt * 8) * 1024 + rem);
  }
  __syncthreads();

  float rs100[4];
#pragma unroll
  for (int s = 0; s < 4; ++s)
    rs100[s] = rsp[n0b + wn * 64 + s * 16 + l15] * (100.f / 1024.f);

  float ls[4], su[4], sv[4];
#pragma unroll
  for (int s = 0; s < 4; ++s) { ls[s] = su[s] = sv[s] = 0.f; }

  v4f acc[4][4];
#pragma unroll
  for (int f = 0; f < 4; ++f)
#pragma unroll
    for (int s = 0; s < 4; ++s)
#pragma unroll
      for (int e = 0; e < 4; ++e) acc[f][s][e] = 0.f;

  const float ubase = (float)(wm * 64 + lq * 4);
  const float vbase = (float)(ps * 8);

  v8h phA[4], qhA[4], phB[4], qhB[4];
  LOADT(phA, qhA, 0);

  for (int t2 = 0; t2 < 64; t2 += 2) {
    LOADT(phB, qhB, t2 + 1);
    MFMAT(phA, qhA);
    if (t2 + 2 < 64) LOADT(phA, qhA, t2 + 2);
    MFMAT(phB, qhB);

    if (((t2 + 1) & 7) == 7) {           // K complete for this 128-px tile
      const int pt = t2 >> 3;
      const float vb = vbase + (float)pt;
      float4 rt4[4];
#pragma unroll
      for (int f = 0; f < 4; ++f)
        rt4[f] = *(const float4*)(rtp + pt * 128 + wm * 64 + f * 16 + lq * 4);
#pragma unroll
      for (int s = 0; s < 4; ++s) {
        float te = 0.f, tu = 0.f;
#pragma unroll
        for (int f = 0; f < 4; ++f)
#pragma unroll
          for (int e = 0; e < 4; ++e) {
            float x = __expf(fmaf(acc[f][s][e], rs100[s] * GETJ(rt4[f], e), -100.f));
            te += x;
            tu = fmaf(x, ubase + (float)(f * 16 + e), tu);
            acc[f][s][e] = 0.f;
          }
        ls[s] += te;
        su[s] += tu;
        sv[s] = fmaf(vb, te, sv[s]);
      }
    }
  }

  // merge 8 partials (wm x lq) per keypoint — plain sums
  __syncthreads();                 // all Qh reads done; reuse LDS as merge buf
  float4* red = (float4*)QSM;      // [128 n][8 slots]
#pragma unroll
  for (int s = 0; s < 4; ++s)
    red[(wn * 64 + s * 16 + l15) * 8 + wm * 4 + lq] = make_float4(ls[s], su[s], sv[s], 0.f);
  __syncthreads();
  if (tid < NT) {
    float L = 0.f, SU = 0.f, SV = 0.f;
#pragma unroll
    for (int i = 0; i < 8; ++i) {
      float4 q = red[tid * 8 + i];
      L += q.x; SU += q.y; SV += q.z;
    }
    partials[(size_t)(b * NKP + n0b + tid) * PSPLIT + ps] = make_float4(L, SU, SV, 0.f);
  }
}

// Fused partial-merge + coords + bilinear weights (fast path).
__global__ __launch_bounds__(256) void k_weights2(const float* __restrict__ kd,
                                                  const float* __restrict__ dd,
                                                  const float* __restrict__ ks,
                                                  const float* __restrict__ sd,
                                                  const float* __restrict__ ws_in,
                                                  const float4* __restrict__ partials,
                                                  float* __restrict__ out) {
  int wid = blockIdx.x * 4 + (threadIdx.x >> 6);
  int lane = threadIdx.x & 63;
  int b = wid >> 10, n = wid & (NKP - 1);

  float L = 0.f, SU = 0.f, SV = 0.f;
  if (lane < PSPLIT) {
    float4 q = partials[(size_t)wid * PSPLIT + lane];
    L = q.x; SU = q.y; SV = q.z;
  }
#pragma unroll
  for (int o = 1; o < 64; o <<= 1) {
    L += __shfl_xor(L, o, 64);
    SU += __shfl_xor(SU, o, 64);
    SV += __shfl_xor(SV, o, 64);
  }
  float pu = SU / L, pv = SV / L;
  if (lane == 0) {
    out[wid * 2 + 0] = pu;
    out[wid * 2 + 1] = pv;
  }

  float x = pu * (128.f / 127.f) - 0.5f;
  float y = pv * (128.f / 127.f) - 0.5f;
  float x0 = floorf(x), y0 = floorf(y);
  float wx1 = x - x0, wx0 = 1.f - wx1;
  float wy1 = y - y0, wy0 = 1.f - wy1;

  float xs[4] = {x0, x0 + 1.f, x0, x0 + 1.f};
  float ys[4] = {y0, y0, y0 + 1.f, y0 + 1.f};
  float wsc[4] = {wx0 * wy0, wx1 * wy0, wx0 * wy1, wx1 * wy1};
  float cw[4];
  int co[4];
#pragma unroll
  for (int k = 0; k < 4; ++k) {
    bool inb = (xs[k] >= 0.f) && (xs[k] < (float)WW) && (ys[k] >= 0.f) && (ys[k] < (float)HH);
    cw[k] = inb ? wsc[k] : 0.f;
    int cx = min(max((int)xs[k], 0), WW - 1);
    int cy = min(max((int)ys[k], 0), HH - 1);
    co[k] = cy * WW + cx;
  }

  const float* tgt = dd + (size_t)(2 * b + 1) * CDIM * HWPX;
  const float* srcd = kd + (size_t)(2 * b) * CDIM * NKP;
  float accd = 0.f;
  for (int c = lane; c < CDIM; c += 64) {
    const float* tc = tgt + (size_t)c * HWPX;
    float pd = cw[0] * tc[co[0]] + cw[1] * tc[co[1]] + cw[2] * tc[co[2]] + cw[3] * tc[co[3]];
    float sc = srcd[(size_t)c * NKP + n];
    accd = fmaf(sc, pd, accd);
  }
#pragma unroll
  for (int o = 32; o; o >>= 1) accd += __shfl_xor(accd, o, 64);

  if (lane == 0) {
    const float* ssc = sd + (size_t)(2 * b + 1) * HWPX;
    float psc = cw[0] * ssc[co[0]] + cw[1] * ssc[co[1]] + cw[2] * ssc[co[2]] + cw[3] * ssc[co[3]];
    float dms = accd * ws_in[WS_RS + b * NKP + n] * (1.f / (float)CDIM);
    float w = 0.5f * (dms + 1.f) * ks[(size_t)(2 * b) * NKP + n] * psc;
    out[BN * NKP * 2 + b * NKP + n] = w;
  }
}

// ======================= fallback path (round-4, passed) =======================

#define FB_NT 128
#define FB_PSPLIT 16
#define FB_PPB 1024
#define MT 256
#define KC 32
#define PT_STEPS (FB_PPB/MT)
#define CHUNKS (CDIM/KC)
#define KROW 80
#define PH_OFF 0
#define PL_OFF 20480
#define QH_OFF 40960
#define QL_OFF 51200
#define RSL_OFF 61440
#define RTL_OFF 61952
#define SM_BYTES 62976

__global__ __launch_bounds__(256) void k_rnorm_src(const float* __restrict__ kd,
                                                   float* __restrict__ ws) {
  int idx = blockIdx.x * 256 + threadIdx.x;
  int b = idx >> 10, n = idx & (NKP - 1);
  const float* p = kd + (size_t)(2 * b) * CDIM * NKP + n;
  float s = 0.f;
  for (int c = 0; c < CDIM; ++c) { float v = p[(size_t)c * NKP]; s = fmaf(v, v, s); }
  ws[WS_RS + idx] = 1.f / fmaxf(sqrtf(s), 1e-12f);
}

__global__ __launch_bounds__(256) void k_rnorm_tgt(const float* __restrict__ dd,
                                                   float* __restrict__ ws) {
  int idx = blockIdx.x * 256 + threadIdx.x;
  int b = idx >> 14, m = idx & (HWPX - 1);
  const float* p = dd + (size_t)(2 * b + 1) * CDIM * HWPX + m;
  float s = 0.f;
  for (int c = 0; c < CDIM; ++c) { float v = p[(size_t)c * HWPX]; s = fmaf(v, v, s); }
  ws[WS_RT + idx] = 1.f / fmaxf(sqrtf(s), 1e-12f);
}

__global__ __launch_bounds__(256, 2) void k_match(const float* __restrict__ kd,
                                                  const float* __restrict__ dd,
                                                  const float* __restrict__ wsp,
                                                  float4* __restrict__ partials) {
  __shared__ __align__(16) char SM[SM_BYTES];
  const int tid = threadIdx.x;
  const int w = tid >> 6, lane = tid & 63;
  const int l15 = lane & 15, lq = lane >> 4;
  const int ps = blockIdx.x, nt = blockIdx.y, b = blockIdx.z;
  const int n0b = nt * FB_NT;
  const int p0 = ps * FB_PPB;

  const float* Ag = kd + (size_t)(2 * b) * CDIM * NKP;
  const float* Bg = dd + (size_t)(2 * b + 1) * CDIM * HWPX;
  const float* rs = wsp + WS_RS + b * NKP;
  const float* rt = wsp + WS_RT + b * HWPX;

  float* rsl = (float*)(SM + RSL_OFF);
  float* rtl = (float*)(SM + RTL_OFF);
  if (tid < FB_NT) rsl[tid] = rs[n0b + tid] * 3.125f;

  const int koct = tid & 3;
  const int mq4 = (tid >> 2) * 4;

  float mx[8], ls[8], su[8], sv[8];
#pragma unroll
  for (int s = 0; s < 8; ++s) { mx[s] = -INFINITY; ls[s] = su[s] = sv[s] = 0.f; }

  const float ubase = (float)((w & 1) * 64 + lq * 4);

  for (int pt = 0; pt < PT_STEPS; ++pt) {
    const int pm0 = p0 + pt * MT;
    __syncthreads();
    rtl[tid] = rt[pm0 + tid] * 32.f;

    v4f acc[4][8];
#pragma unroll
    for (int f = 0; f < 4; ++f)
#pragma unroll
      for (int s = 0; s < 8; ++s)
#pragma unroll
        for (int e = 0; e < 4; ++e) acc[f][s][e] = 0.f;

    for (int kc = 0; kc < CHUNKS; ++kc) {
      __syncthreads();
      {
        const float* Bk = Bg + (size_t)(kc * KC + koct * 8) * HWPX + pm0 + mq4;
        float4 r[8];
#pragma unroll
        for (int rr = 0; rr < 8; ++rr) r[rr] = *(const float4*)(Bk + (size_t)rr * HWPX);
        float4 sc4 = *(const float4*)(rtl + mq4);
#pragma unroll
        for (int j = 0; j < 4; ++j) {
          const float scj = GETJ(sc4, j);
          v8h hi, lo;
#pragma unroll
          for (int rr = 0; rr < 8; ++rr) {
            float v = GETJ(r[rr], j) * scj;
            _Float16 hh = (_Float16)v;
            hi[rr] = hh;
            lo[rr] = (_Float16)(v - (float)hh);
          }
          *(v8h*)(SM + PH_OFF + (mq4 + j) * KROW + koct * 16) = hi;
          *(v8h*)(SM + PL_OFF + (mq4 + j) * KROW + koct * 16) = lo;
        }
      }
      if (tid < 128) {
        const int nq4 = (tid >> 2) * 4;
        const float* Ak = Ag + (size_t)(kc * KC + koct * 8) * NKP + n0b + nq4;
        float4 r[8];
#pragma unroll
        for (int rr = 0; rr < 8; ++rr) r[rr] = *(const float4*)(Ak + (size_t)rr * NKP);
        float4 sc4 = *(const float4*)(rsl + nq4);
#pragma unroll
        for (int j = 0; j < 4; ++j) {
          const float scj = GETJ(sc4, j);
          v8h hi, lo;
#pragma unroll
          for (int rr = 0; rr < 8; ++rr) {
            float v = GETJ(r[rr], j) * scj;
            _Float16 hh = (_Float16)v;
            hi[rr] = hh;
            lo[rr] = (_Float16)(v - (float)hh);
          }
          *(v8h*)(SM + QH_OFF + (nq4 + j) * KROW + koct * 16) = hi;
          *(v8h*)(SM + QL_OFF + (nq4 + j) * KROW + koct * 16) = lo;
        }
      }
      __syncthreads();

      v8h PHf[4], PLf[4];
#pragma unroll
      for (int f = 0; f < 4; ++f) {
        const int row = w * 64 + f * 16 + l15;
        PHf[f] = *(const v8h*)(SM + PH_OFF + row * KROW + lq * 16);
        PLf[f] = *(const v8h*)(SM + PL_OFF + row * KROW + lq * 16);
      }
#pragma unroll
      for (int s = 0; s < 8; ++s) {
        const int col = s * 16 + l15;
        v8h qh = *(const v8h*)(SM + QH_OFF + col * KROW + lq * 16);
        v8h ql = *(const v8h*)(SM + QL_OFF + col * KROW + lq * 16);
#pragma unroll
        for (int f = 0; f < 4; ++f) {
          acc[f][s] = __builtin_amdgcn_mfma_f32_16x16x32_f16(PHf[f], qh, acc[f][s], 0, 0, 0);
          acc[f][s] = __builtin_amdgcn_mfma_f32_16x16x32_f16(PLf[f], qh, acc[f][s], 0, 0, 0);
          acc[f][s] = __builtin_amdgcn_mfma_f32_16x16x32_f16(PHf[f], ql, acc[f][s], 0, 0, 0);
        }
      }
    }

    const float vb = (float)((pm0 >> 7) + (w >> 1));
#pragma unroll
    for (int s = 0; s < 8; ++s) {
      float tm = -INFINITY;
#pragma unroll
      for (int f = 0; f < 4; ++f)
#pragma unroll
        for (int e = 0; e < 4; ++e) tm = fmaxf(tm, acc[f][s][e]);
      float nm = fmaxf(mx[s], tm);
      float scf = __expf(mx[s] - nm);
      float te = 0.f, tu = 0.f;
#pragma unroll
      for (int f = 0; f < 4; ++f)
#pragma unroll
        for (int e = 0; e < 4; ++e) {
          float x = __expf(acc[f][s][e] - nm);
          te += x;
          tu = fmaf(x, ubase + (float)(f * 16 + e), tu);
        }
      ls[s] = ls[s] * scf + te;
      su[s] = su[s] * scf + tu;
      sv[s] = sv[s] * scf + vb * te;
      mx[s] = nm;
    }
  }

  __syncthreads();
  float4* red = (float4*)SM;
#pragma unroll
  for (int s = 0; s < 8; ++s)
    red[(s * 16 + l15) * 16 + w * 4 + lq] = make_float4(mx[s], ls[s], su[s], sv[s]);
  __syncthreads();
  if (tid < FB_NT) {
    float M = -INFINITY, L = 0.f, SU = 0.f, SV = 0.f;
#pragma unroll
    for (int i = 0; i < 16; ++i) {
      float4 q = red[tid * 16 + i];
      float nm2 = fmaxf(M, q.x);
      float e1 = __expf(M - nm2), e2 = __expf(q.x - nm2);
      L = L * e1 + q.y * e2; SU = SU * e1 + q.z * e2; SV = SV * e1 + q.w * e2;
      M = nm2;
    }
    partials[(size_t)(b * NKP + n0b + tid) * FB_PSPLIT + ps] = make_float4(M, L, SU, SV);
  }
}

__global__ __launch_bounds__(256) void k_coords(const float4* __restrict__ partials,
                                                float* __restrict__ out) {
  int row = blockIdx.x * 256 + threadIdx.x;
  float M = -INFINITY, L = 0.f, SU = 0.f, SV = 0.f;
  for (int i = 0; i < FB_PSPLIT; ++i) {
    float4 q = partials[(size_t)row * FB_PSPLIT + i];
    float nm = fmaxf(M, q.x);
    float e1 = __expf(M - nm), e2 = __expf(q.x - nm);
    L = L * e1 + q.y * e2; SU = SU * e1 + q.z * e2; SV = SV * e1 + q.w * e2;
    M = nm;
  }
  out[row * 2 + 0] = SU / L;
  out[row * 2 + 1] = SV / L;
}

__global__ __launch_bounds__(256) void k_weights(const float* __restrict__ kd,
                                                 const float* __restrict__ dd,
                                                 const float* __restrict__ ks,
                                                 const float* __restrict__ sd,
                                                 const float* __restrict__ ws_in,
                                                 float* __restrict__ out) {
  int wid = blockIdx.x * 4 + (threadIdx.x >> 6);
  int lane = threadIdx.x & 63;
  int b = wid >> 10, n = wid & (NKP - 1);

  float pu = out[wid * 2 + 0];
  float pv = out[wid * 2 + 1];
  float x = pu * (128.f / 127.f) - 0.5f;
  float y = pv * (128.f / 127.f) - 0.5f;
  float x0 = floorf(x), y0 = floorf(y);
  float wx1 = x - x0, wx0 = 1.f - wx1;
  float wy1 = y - y0, wy0 = 1.f - wy1;

  float xs[4] = {x0, x0 + 1.f, x0, x0 + 1.f};
  float ys[4] = {y0, y0, y0 + 1.f, y0 + 1.f};
  float wsc[4] = {wx0 * wy0, wx1 * wy0, wx0 * wy1, wx1 * wy1};
  float cw[4];
  int co[4];
#pragma unroll
  for (int k = 0; k < 4; ++k) {
    bool inb = (xs[k] >= 0.f) && (xs[k] < (float)WW) && (ys[k] >= 0.f) && (ys[k] < (float)HH);
    cw[k] = inb ? wsc[k] : 0.f;
    int cx = min(max((int)xs[k], 0), WW - 1);
    int cy = min(max((int)ys[k], 0), HH - 1);
    co[k] = cy * WW + cx;
  }

  const float* tgt = dd + (size_t)(2 * b + 1) * CDIM * HWPX;
  const float* srcd = kd + (size_t)(2 * b) * CDIM * NKP;
  float accd = 0.f;
  for (int c = lane; c < CDIM; c += 64) {
    const float* tc = tgt + (size_t)c * HWPX;
    float pd = cw[0] * tc[co[0]] + cw[1] * tc[co[1]] + cw[2] * tc[co[2]] + cw[3] * tc[co[3]];
    float sc = srcd[(size_t)c * NKP + n];
    accd = fmaf(sc, pd, accd);
  }
#pragma unroll
  for (int o = 32; o; o >>= 1) accd += __shfl_xor(accd, o, 64);

  if (lane == 0) {
    const float* ssc = sd + (size_t)(2 * b + 1) * HWPX;
    float psc = cw[0] * ssc[co[0]] + cw[1] * ssc[co[1]] + cw[2] * ssc[co[2]] + cw[3] * ssc[co[3]];
    float dms = accd * ws_in[WS_RS + b * NKP + n] * (1.f / (float)CDIM);
    float w = 0.5f * (dms + 1.f) * ks[(size_t)(2 * b) * NKP + n] * psc;
    out[BN * NKP * 2 + b * NKP + n] = w;
  }
}

extern "C" void kernel_launch(void* const* d_in, const int* in_sizes, int n_in,
                              void* d_out, int out_size, void* d_ws, size_t ws_size,
                              hipStream_t stream) {
  const float* ks = (const float*)d_in[0];
  const float* kd = (const float*)d_in[1];
  const float* sd = (const float*)d_in[2];
  const float* dd = (const float*)d_in[3];
  float* out = (float*)d_out;
  float* ws = (float*)d_ws;

  if (ws_size >= (size_t)WS_NEED) {
    char* pq = (char*)d_ws + WS_PQ_B;
    char* pp = (char*)d_ws + WS_PP_B;
    hipLaunchKernelGGL(k_prep, dim3(544), dim3(256), 0, stream, kd, dd, ws, pq, pp);
    hipLaunchKernelGGL(k_match3, dim3(512), dim3(256), 0, stream,
                       pp, pq, ws, (float4*)(ws + WS_PART));
    hipLaunchKernelGGL(k_weights2, dim3(BN * NKP / 4), dim3(256), 0, stream,
                       kd, dd, ks, sd, ws, (const float4*)(ws + WS_PART), out);
  } else {
    hipLaunchKernelGGL(k_rnorm_src, dim3(BN * NKP / 256), dim3(256), 0, stream, kd, ws);
    hipLaunchKernelGGL(k_rnorm_tgt, dim3(BN * HWPX / 256), dim3(256), 0, stream, dd, ws);
    hipLaunchKernelGGL(k_match, dim3(FB_PSPLIT, NKP / FB_NT, BN), dim3(256), 0, stream,
                       kd, dd, ws, (float4*)(ws + WS_PART));
    hipLaunchKernelGGL(k_coords, dim3(BN * NKP / 256), dim3(256), 0, stream,
                       (const float4*)(ws + WS_PART), out);
    hipLaunchKernelGGL(k_weights, dim3(BN * NKP / 4), dim3(256), 0, stream,
                       kd, dd, ks, sd, ws, out);
  }
}

// Round 16
// 70.722 us; speedup vs baseline: 2.8112x; 1.3561x over previous
//
#include <hip/hip_runtime.h>
#include <math.h>

#define BN 4
#define CDIM 256
#define NKP 1024
#define HH 128
#define WW 128
#define HWPX (HH*WW)

#define PSPLIT 16
#define PPB 1024
#define NT 128

// ---- workspace layout ----
#define WS_RS 0
#define WS_RT (WS_RS + BN*NKP)
#define WS_PART (WS_RT + BN*HWPX)          // float4[BN*NKP*PSPLIT]
#define WS_PQ_B 1327104u                   // [b][kc][64 frag]x1024B = 4 MB region
#define WS_PP_B 5521408u                   // [b][kc][1024 frag]x1024B (HI ONLY) = 32 MB
#define WS_NEED 39075840u

typedef __attribute__((ext_vector_type(8)))  _Float16 v8h;
typedef __attribute__((ext_vector_type(4)))  float v4f;

#define GETJ(v, j) ((j) == 0 ? (v).x : (j) == 1 ? (v).y : (j) == 2 ? (v).z : (v).w)

// ======================= fast path =======================

// Fused prep (r15): 2 threads per element; even/odd lanes split channels into
// halves (4 kc-planes each); norm combined via shfl_xor(1).
// Blocks 0..511: P (dd) -> f16 HI. Blocks 512..543: Q (kd) -> f16 HI.
// Fragment block = 1024 B: [4 ko][16 col][16 B]; frag index = col>>4.
__global__ __launch_bounds__(256) void k_prep(const float* __restrict__ kd,
                                              const float* __restrict__ dd,
                                              float* __restrict__ wsf,
                                              char* __restrict__ pq,
                                              char* __restrict__ pp) {
  const int tid = threadIdx.x;
  const int half = tid & 1;
  const int kc0 = half * 4;
  if (blockIdx.x < 512) {
    int id = blockIdx.x;                 // 512 = b*128 + mb
    int b = id >> 7;
    int m = (id & 127) * 128 + (tid >> 1);
    const float* p = dd + (size_t)(2 * b + 1) * CDIM * HWPX + m;
    char* mb = pp + (size_t)b * 8388608 + (m >> 4) * 1024 + (m & 15) * 16;
    float s = 0.f;
#pragma unroll
    for (int kc = 0; kc < 4; ++kc) {
#pragma unroll
      for (int ko = 0; ko < 4; ++ko) {
        v8h hi;
#pragma unroll
        for (int j = 0; j < 8; ++j) {
          float v = p[(size_t)((kc0 + kc) * 32 + ko * 8 + j) * HWPX];
          s = fmaf(v, v, s);
          hi[j] = (_Float16)(v * 32.f);
        }
        *(v8h*)(mb + (size_t)(kc0 + kc) * 1048576 + ko * 256) = hi;
      }
    }
    s += __shfl_xor(s, 1, 64);
    if (half == 0) wsf[WS_RT + b * HWPX + m] = 1.f / fmaxf(sqrtf(s), 1e-12f);
  } else {
    int id = blockIdx.x - 512;           // 32 = b*8 + nb
    int b = id >> 3;
    int n = (id & 7) * 128 + (tid >> 1);
    const float* p = kd + (size_t)(2 * b) * CDIM * NKP + n;
    char* qb = pq + (size_t)b * 1048576 + (n >> 4) * 1024 + (n & 15) * 16;
    float s = 0.f;
#pragma unroll
    for (int kc = 0; kc < 4; ++kc) {
#pragma unroll
      for (int ko = 0; ko < 4; ++ko) {
        v8h hi;
#pragma unroll
        for (int j = 0; j < 8; ++j) {
          float v = p[(size_t)((kc0 + kc) * 32 + ko * 8 + j) * NKP];
          s = fmaf(v, v, s);
          hi[j] = (_Float16)(v * 32.f);
        }
        *(v8h*)(qb + (size_t)(kc0 + kc) * 131072 + ko * 256) = hi;
      }
    }
    s += __shfl_xor(s, 1, 64);
    if (half == 0) wsf[WS_RS + b * NKP + n] = 1.f / fmaxf(sqrtf(s), 1e-12f);
  }
}

// Zero-barrier-loop fused MFMA GEMM + fixed-shift softmax, 1-term f16
// (exact r12 config): NT=128, Qh plane wholly in 64 KB LDS, grid 512 =
// exactly 2 blocks/CU, A/B double-buffered fragments.
#define LOADT(ph, qh, t) do {                                                  \
  const int pt_ = (t) >> 3, kc_ = (t) & 7;                                     \
  const char* Pb_ = ppb + (size_t)kc_ * 1048576 + (size_t)(frp + pt_ * 8) * 1024; \
  const char* Qs_ = QSM + kc_ * 8192 + wn * 4096;                              \
  _Pragma("unroll")                                                            \
  for (int f_ = 0; f_ < 4; ++f_) {                                             \
    ph[f_] = *(const v8h*)(Pb_ + f_ * 1024 + lane16);                          \
    qh[f_] = *(const v8h*)(Qs_ + f_ * 1024 + lane16);                          \
  }                                                                            \
} while (0)

#define MFMAT(ph, qh)                                                          \
  __builtin_amdgcn_s_setprio(1);                                               \
  _Pragma("unroll")                                                            \
  for (int s_ = 0; s_ < 4; ++s_) {                                             \
    _Pragma("unroll")                                                          \
    for (int f_ = 0; f_ < 4; ++f_) {                                           \
      acc[f_][s_] = __builtin_amdgcn_mfma_f32_16x16x32_f16(ph[f_], qh[s_], acc[f_][s_], 0, 0, 0); \
    }                                                                          \
  }                                                                            \
  __builtin_amdgcn_s_setprio(0);

__global__ __launch_bounds__(256, 2) void k_match3(const char* __restrict__ pp,
                                                   const char* __restrict__ pq,
                                                   const float* __restrict__ wsf,
                                                   float4* __restrict__ partials) {
  __shared__ __align__(16) char QSM[65536];
  const int tid = threadIdx.x;
  const int w = tid >> 6, lane = tid & 63;
  const int l15 = lane & 15, lq = lane >> 4;
  const int wm = w & 1, wn = w >> 1;

  // XCD-chunked grid: fid = b*128 + ps*8 + nt; XCD x owns b = x>>1, 8 ps values.
  const int raw = blockIdx.x;
  const int fid = (raw & 7) * 64 + (raw >> 3);
  const int b = fid >> 7, ps = (fid >> 3) & 15, nt = fid & 7;
  const int n0b = nt * NT;

  const char* ppb = pp + (size_t)b * 8388608;
  const char* pqb = pq + (size_t)b * 1048576;
  const float* rtp = wsf + WS_RT + b * HWPX + ps * PPB;
  const float* rsp = wsf + WS_RS + b * NKP;

  const int frp = ps * 64 + wm * 4;
  const unsigned lane16 = (unsigned)lane * 16;

  // ---- stage Qh plane (block's 128 n, all 8 kc) into LDS: 64 KB ----
#pragma unroll
  for (int j = 0; j < 16; ++j) {
    int off = j * 4096 + tid * 16;
    int kc = off >> 13, rem = off & 8191;   // rem = f*1024 + l16, f<8
    *(float4*)(QSM + off) =
        *(const float4*)(pqb + (size_t)kc * 131072 + (size_t)(nt * 8) * 1024 + rem);
  }
  __syncthreads();

  float rs100[4];
#pragma unroll
  for (int s = 0; s < 4; ++s)
    rs100[s] = rsp[n0b + wn * 64 + s * 16 + l15] * (100.f / 1024.f);

  float ls[4], su[4], sv[4];
#pragma unroll
  for (int s = 0; s < 4; ++s) { ls[s] = su[s] = sv[s] = 0.f; }

  v4f acc[4][4];
#pragma unroll
  for (int f = 0; f < 4; ++f)
#pragma unroll
    for (int s = 0; s < 4; ++s)
#pragma unroll
      for (int e = 0; e < 4; ++e) acc[f][s][e] = 0.f;

  const float ubase = (float)(wm * 64 + lq * 4);
  const float vbase = (float)(ps * 8);

  v8h phA[4], qhA[4], phB[4], qhB[4];
  LOADT(phA, qhA, 0);

  for (int t2 = 0; t2 < 64; t2 += 2) {
    LOADT(phB, qhB, t2 + 1);
    MFMAT(phA, qhA);
    if (t2 + 2 < 64) LOADT(phA, qhA, t2 + 2);
    MFMAT(phB, qhB);

    if (((t2 + 1) & 7) == 7) {           // K complete for this 128-px tile
      const int pt = t2 >> 3;
      const float vb = vbase + (float)pt;
      float4 rt4[4];
#pragma unroll
      for (int f = 0; f < 4; ++f)
        rt4[f] = *(const float4*)(rtp + pt * 128 + wm * 64 + f * 16 + lq * 4);
#pragma unroll
      for (int s = 0; s < 4; ++s) {
        float te = 0.f, tu = 0.f;
#pragma unroll
        for (int f = 0; f < 4; ++f)
#pragma unroll
          for (int e = 0; e < 4; ++e) {
            float x = __expf(fmaf(acc[f][s][e], rs100[s] * GETJ(rt4[f], e), -100.f));
            te += x;
            tu = fmaf(x, ubase + (float)(f * 16 + e), tu);
            acc[f][s][e] = 0.f;
          }
        ls[s] += te;
        su[s] += tu;
        sv[s] = fmaf(vb, te, sv[s]);
      }
    }
  }

  // merge 8 partials (wm x lq) per keypoint — plain sums
  __syncthreads();                 // all Qh reads done; reuse LDS as merge buf
  float4* red = (float4*)QSM;      // [128 n][8 slots]
#pragma unroll
  for (int s = 0; s < 4; ++s)
    red[(wn * 64 + s * 16 + l15) * 8 + wm * 4 + lq] = make_float4(ls[s], su[s], sv[s], 0.f);
  __syncthreads();
  if (tid < NT) {
    float L = 0.f, SU = 0.f, SV = 0.f;
#pragma unroll
    for (int i = 0; i < 8; ++i) {
      float4 q = red[tid * 8 + i];
      L += q.x; SU += q.y; SV += q.z;
    }
    partials[(size_t)(b * NKP + n0b + tid) * PSPLIT + ps] = make_float4(L, SU, SV, 0.f);
  }
}

// Fused partial-merge + coords + bilinear weights. Desc dot gathered from the
// prepped f16 arrays (pp/pq): lane = corner(lane>>4) x chunk(lane&15, x2);
// 16-B loads replace per-channel 4-B gathers (~5x less cacheline traffic).
__global__ __launch_bounds__(256) void k_weights2(const char* __restrict__ pp,
                                                  const char* __restrict__ pq,
                                                  const float* __restrict__ ks,
                                                  const float* __restrict__ sd,
                                                  const float* __restrict__ ws_in,
                                                  const float4* __restrict__ partials,
                                                  float* __restrict__ out) {
  int wid = blockIdx.x * 4 + (threadIdx.x >> 6);
  int lane = threadIdx.x & 63;
  int b = wid >> 10, n = wid & (NKP - 1);

  float L = 0.f, SU = 0.f, SV = 0.f;
  if (lane < PSPLIT) {
    float4 q = partials[(size_t)wid * PSPLIT + lane];
    L = q.x; SU = q.y; SV = q.z;
  }
#pragma unroll
  for (int o = 1; o < 64; o <<= 1) {
    L += __shfl_xor(L, o, 64);
    SU += __shfl_xor(SU, o, 64);
    SV += __shfl_xor(SV, o, 64);
  }
  float pu = SU / L, pv = SV / L;
  if (lane == 0) {
    out[wid * 2 + 0] = pu;
    out[wid * 2 + 1] = pv;
  }

  float x = pu * (128.f / 127.f) - 0.5f;
  float y = pv * (128.f / 127.f) - 0.5f;
  float x0 = floorf(x), y0 = floorf(y);
  float wx1 = x - x0, wx0 = 1.f - wx1;
  float wy1 = y - y0, wy0 = 1.f - wy1;

  float xs[4] = {x0, x0 + 1.f, x0, x0 + 1.f};
  float ys[4] = {y0, y0, y0 + 1.f, y0 + 1.f};
  float wsc[4] = {wx0 * wy0, wx1 * wy0, wx0 * wy1, wx1 * wy1};
  float cw[4];
  int co[4];
#pragma unroll
  for (int k = 0; k < 4; ++k) {
    bool inb = (xs[k] >= 0.f) && (xs[k] < (float)WW) && (ys[k] >= 0.f) && (ys[k] < (float)HH);
    cw[k] = inb ? wsc[k] : 0.f;
    int cx = min(max((int)xs[k], 0), WW - 1);
    int cy = min(max((int)ys[k], 0), HH - 1);
    co[k] = cy * WW + cx;
  }

  // gather dot from prepped f16 (both operands x32 -> descale by 1/1024)
  const int k = lane >> 4;
  const int m = co[k];
  const char* qb = pq + (size_t)b * 1048576 + (n >> 4) * 1024 + (n & 15) * 16;
  const char* pb = pp + (size_t)b * 8388608 + (m >> 4) * 1024 + (m & 15) * 16;
  float accd = 0.f;
#pragma unroll
  for (int i = 0; i < 2; ++i) {
    int chunk = (lane & 15) + 16 * i;
    int kc = chunk >> 2, ko = chunk & 3;
    v8h t8 = *(const v8h*)(pb + (size_t)kc * 1048576 + ko * 256);
    v8h s8 = *(const v8h*)(qb + (size_t)kc * 131072 + ko * 256);
#pragma unroll
    for (int j = 0; j < 8; ++j) accd = fmaf((float)t8[j], (float)s8[j], accd);
  }
  accd *= cw[k];
#pragma unroll
  for (int o = 32; o; o >>= 1) accd += __shfl_xor(accd, o, 64);

  if (lane == 0) {
    const float* ssc = sd + (size_t)(2 * b + 1) * HWPX;
    float psc = cw[0] * ssc[co[0]] + cw[1] * ssc[co[1]] + cw[2] * ssc[co[2]] + cw[3] * ssc[co[3]];
    float dms = accd * ws_in[WS_RS + b * NKP + n] * (1.f / (1024.f * 256.f));
    float w = 0.5f * (dms + 1.f) * ks[(size_t)(2 * b) * NKP + n] * psc;
    out[BN * NKP * 2 + b * NKP + n] = w;
  }
}

// ======================= fallback path (round-4, passed) =======================

#define FB_NT 128
#define FB_PSPLIT 16
#define FB_PPB 1024
#define MT 256
#define KC 32
#define PT_STEPS (FB_PPB/MT)
#define CHUNKS (CDIM/KC)
#define KROW 80
#define PH_OFF 0
#define PL_OFF 20480
#define QH_OFF 40960
#define QL_OFF 51200
#define RSL_OFF 61440
#define RTL_OFF 61952
#define SM_BYTES 62976

__global__ __launch_bounds__(256) void k_rnorm_src(const float* __restrict__ kd,
                                                   float* __restrict__ ws) {
  int idx = blockIdx.x * 256 + threadIdx.x;
  int b = idx >> 10, n = idx & (NKP - 1);
  const float* p = kd + (size_t)(2 * b) * CDIM * NKP + n;
  float s = 0.f;
  for (int c = 0; c < CDIM; ++c) { float v = p[(size_t)c * NKP]; s = fmaf(v, v, s); }
  ws[WS_RS + idx] = 1.f / fmaxf(sqrtf(s), 1e-12f);
}

__global__ __launch_bounds__(256) void k_rnorm_tgt(const float* __restrict__ dd,
                                                   float* __restrict__ ws) {
  int idx = blockIdx.x * 256 + threadIdx.x;
  int b = idx >> 14, m = idx & (HWPX - 1);
  const float* p = dd + (size_t)(2 * b + 1) * CDIM * HWPX + m;
  float s = 0.f;
  for (int c = 0; c < CDIM; ++c) { float v = p[(size_t)c * HWPX]; s = fmaf(v, v, s); }
  ws[WS_RT + idx] = 1.f / fmaxf(sqrtf(s), 1e-12f);
}

__global__ __launch_bounds__(256, 2) void k_match(const float* __restrict__ kd,
                                                  const float* __restrict__ dd,
                                                  const float* __restrict__ wsp,
                                                  float4* __restrict__ partials) {
  __shared__ __align__(16) char SM[SM_BYTES];
  const int tid = threadIdx.x;
  const int w = tid >> 6, lane = tid & 63;
  const int l15 = lane & 15, lq = lane >> 4;
  const int ps = blockIdx.x, nt = blockIdx.y, b = blockIdx.z;
  const int n0b = nt * FB_NT;
  const int p0 = ps * FB_PPB;

  const float* Ag = kd + (size_t)(2 * b) * CDIM * NKP;
  const float* Bg = dd + (size_t)(2 * b + 1) * CDIM * HWPX;
  const float* rs = wsp + WS_RS + b * NKP;
  const float* rt = wsp + WS_RT + b * HWPX;

  float* rsl = (float*)(SM + RSL_OFF);
  float* rtl = (float*)(SM + RTL_OFF);
  if (tid < FB_NT) rsl[tid] = rs[n0b + tid] * 3.125f;

  const int koct = tid & 3;
  const int mq4 = (tid >> 2) * 4;

  float mx[8], ls[8], su[8], sv[8];
#pragma unroll
  for (int s = 0; s < 8; ++s) { mx[s] = -INFINITY; ls[s] = su[s] = sv[s] = 0.f; }

  const float ubase = (float)((w & 1) * 64 + lq * 4);

  for (int pt = 0; pt < PT_STEPS; ++pt) {
    const int pm0 = p0 + pt * MT;
    __syncthreads();
    rtl[tid] = rt[pm0 + tid] * 32.f;

    v4f acc[4][8];
#pragma unroll
    for (int f = 0; f < 4; ++f)
#pragma unroll
      for (int s = 0; s < 8; ++s)
#pragma unroll
        for (int e = 0; e < 4; ++e) acc[f][s][e] = 0.f;

    for (int kc = 0; kc < CHUNKS; ++kc) {
      __syncthreads();
      {
        const float* Bk = Bg + (size_t)(kc * KC + koct * 8) * HWPX + pm0 + mq4;
        float4 r[8];
#pragma unroll
        for (int rr = 0; rr < 8; ++rr) r[rr] = *(const float4*)(Bk + (size_t)rr * HWPX);
        float4 sc4 = *(const float4*)(rtl + mq4);
#pragma unroll
        for (int j = 0; j < 4; ++j) {
          const float scj = GETJ(sc4, j);
          v8h hi, lo;
#pragma unroll
          for (int rr = 0; rr < 8; ++rr) {
            float v = GETJ(r[rr], j) * scj;
            _Float16 hh = (_Float16)v;
            hi[rr] = hh;
            lo[rr] = (_Float16)(v - (float)hh);
          }
          *(v8h*)(SM + PH_OFF + (mq4 + j) * KROW + koct * 16) = hi;
          *(v8h*)(SM + PL_OFF + (mq4 + j) * KROW + koct * 16) = lo;
        }
      }
      if (tid < 128) {
        const int nq4 = (tid >> 2) * 4;
        const float* Ak = Ag + (size_t)(kc * KC + koct * 8) * NKP + n0b + nq4;
        float4 r[8];
#pragma unroll
        for (int rr = 0; rr < 8; ++rr) r[rr] = *(const float4*)(Ak + (size_t)rr * NKP);
        float4 sc4 = *(const float4*)(rsl + nq4);
#pragma unroll
        for (int j = 0; j < 4; ++j) {
          const float scj = GETJ(sc4, j);
          v8h hi, lo;
#pragma unroll
          for (int rr = 0; rr < 8; ++rr) {
            float v = GETJ(r[rr], j) * scj;
            _Float16 hh = (_Float16)v;
            hi[rr] = hh;
            lo[rr] = (_Float16)(v - (float)hh);
          }
          *(v8h*)(SM + QH_OFF + (nq4 + j) * KROW + koct * 16) = hi;
          *(v8h*)(SM + QL_OFF + (nq4 + j) * KROW + koct * 16) = lo;
        }
      }
      __syncthreads();

      v8h PHf[4], PLf[4];
#pragma unroll
      for (int f = 0; f < 4; ++f) {
        const int row = w * 64 + f * 16 + l15;
        PHf[f] = *(const v8h*)(SM + PH_OFF + row * KROW + lq * 16);
        PLf[f] = *(const v8h*)(SM + PL_OFF + row * KROW + lq * 16);
      }
#pragma unroll
      for (int s = 0; s < 8; ++s) {
        const int col = s * 16 + l15;
        v8h qh = *(const v8h*)(SM + QH_OFF + col * KROW + lq * 16);
        v8h ql = *(const v8h*)(SM + QL_OFF + col * KROW + lq * 16);
#pragma unroll
        for (int f = 0; f < 4; ++f) {
          acc[f][s] = __builtin_amdgcn_mfma_f32_16x16x32_f16(PHf[f], qh, acc[f][s], 0, 0, 0);
          acc[f][s] = __builtin_amdgcn_mfma_f32_16x16x32_f16(PLf[f], qh, acc[f][s], 0, 0, 0);
          acc[f][s] = __builtin_amdgcn_mfma_f32_16x16x32_f16(PHf[f], ql, acc[f][s], 0, 0, 0);
        }
      }
    }

    const float vb = (float)((pm0 >> 7) + (w >> 1));
#pragma unroll
    for (int s = 0; s < 8; ++s) {
      float tm = -INFINITY;
#pragma unroll
      for (int f = 0; f < 4; ++f)
#pragma unroll
        for (int e = 0; e < 4; ++e) tm = fmaxf(tm, acc[f][s][e]);
      float nm = fmaxf(mx[s], tm);
      float scf = __expf(mx[s] - nm);
      float te = 0.f, tu = 0.f;
#pragma unroll
      for (int f = 0; f < 4; ++f)
#pragma unroll
        for (int e = 0; e < 4; ++e) {
          float x = __expf(acc[f][s][e] - nm);
          te += x;
          tu = fmaf(x, ubase + (float)(f * 16 + e), tu);
        }
      ls[s] = ls[s] * scf + te;
      su[s] = su[s] * scf + tu;
      sv[s] = sv[s] * scf + vb * te;
      mx[s] = nm;
    }
  }

  __syncthreads();
  float4* red = (float4*)SM;
#pragma unroll
  for (int s = 0; s < 8; ++s)
    red[(s * 16 + l15) * 16 + w * 4 + lq] = make_float4(mx[s], ls[s], su[s], sv[s]);
  __syncthreads();
  if (tid < FB_NT) {
    float M = -INFINITY, L = 0.f, SU = 0.f, SV = 0.f;
#pragma unroll
    for (int i = 0; i < 16; ++i) {
      float4 q = red[tid * 16 + i];
      float nm2 = fmaxf(M, q.x);
      float e1 = __expf(M - nm2), e2 = __expf(q.x - nm2);
      L = L * e1 + q.y * e2; SU = SU * e1 + q.z * e2; SV = SV * e1 + q.w * e2;
      M = nm2;
    }
    partials[(size_t)(b * NKP + n0b + tid) * FB_PSPLIT + ps] = make_float4(M, L, SU, SV);
  }
}

__global__ __launch_bounds__(256) void k_coords(const float4* __restrict__ partials,
                                                float* __restrict__ out) {
  int row = blockIdx.x * 256 + threadIdx.x;
  float M = -INFINITY, L = 0.f, SU = 0.f, SV = 0.f;
  for (int i = 0; i < FB_PSPLIT; ++i) {
    float4 q = partials[(size_t)row * FB_PSPLIT + i];
    float nm = fmaxf(M, q.x);
    float e1 = __expf(M - nm), e2 = __expf(q.x - nm);
    L = L * e1 + q.y * e2; SU = SU * e1 + q.z * e2; SV = SV * e1 + q.w * e2;
    M = nm;
  }
  out[row * 2 + 0] = SU / L;
  out[row * 2 + 1] = SV / L;
}

__global__ __launch_bounds__(256) void k_weights(const float* __restrict__ kd,
                                                 const float* __restrict__ dd,
                                                 const float* __restrict__ ks,
                                                 const float* __restrict__ sd,
                                                 const float* __restrict__ ws_in,
                                                 float* __restrict__ out) {
  int wid = blockIdx.x * 4 + (threadIdx.x >> 6);
  int lane = threadIdx.x & 63;
  int b = wid >> 10, n = wid & (NKP - 1);

  float pu = out[wid * 2 + 0];
  float pv = out[wid * 2 + 1];
  float x = pu * (128.f / 127.f) - 0.5f;
  float y = pv * (128.f / 127.f) - 0.5f;
  float x0 = floorf(x), y0 = floorf(y);
  float wx1 = x - x0, wx0 = 1.f - wx1;
  float wy1 = y - y0, wy0 = 1.f - wy1;

  float xs[4] = {x0, x0 + 1.f, x0, x0 + 1.f};
  float ys[4] = {y0, y0, y0 + 1.f, y0 + 1.f};
  float wsc[4] = {wx0 * wy0, wx1 * wy0, wx0 * wy1, wx1 * wy1};
  float cw[4];
  int co[4];
#pragma unroll
  for (int k = 0; k < 4; ++k) {
    bool inb = (xs[k] >= 0.f) && (xs[k] < (float)WW) && (ys[k] >= 0.f) && (ys[k] < (float)HH);
    cw[k] = inb ? wsc[k] : 0.f;
    int cx = min(max((int)xs[k], 0), WW - 1);
    int cy = min(max((int)ys[k], 0), HH - 1);
    co[k] = cy * WW + cx;
  }

  const float* tgt = dd + (size_t)(2 * b + 1) * CDIM * HWPX;
  const float* srcd = kd + (size_t)(2 * b) * CDIM * NKP;
  float accd = 0.f;
  for (int c = lane; c < CDIM; c += 64) {
    const float* tc = tgt + (size_t)c * HWPX;
    float pd = cw[0] * tc[co[0]] + cw[1] * tc[co[1]] + cw[2] * tc[co[2]] + cw[3] * tc[co[3]];
    float sc = srcd[(size_t)c * NKP + n];
    accd = fmaf(sc, pd, accd);
  }
#pragma unroll
  for (int o = 32; o; o >>= 1) accd += __shfl_xor(accd, o, 64);

  if (lane == 0) {
    const float* ssc = sd + (size_t)(2 * b + 1) * HWPX;
    float psc = cw[0] * ssc[co[0]] + cw[1] * ssc[co[1]] + cw[2] * ssc[co[2]] + cw[3] * ssc[co[3]];
    float dms = accd * ws_in[WS_RS + b * NKP + n] * (1.f / (float)CDIM);
    float w = 0.5f * (dms + 1.f) * ks[(size_t)(2 * b) * NKP + n] * psc;
    out[BN * NKP * 2 + b * NKP + n] = w;
  }
}

extern "C" void kernel_launch(void* const* d_in, const int* in_sizes, int n_in,
                              void* d_out, int out_size, void* d_ws, size_t ws_size,
                              hipStream_t stream) {
  const float* ks = (const float*)d_in[0];
  const float* kd = (const float*)d_in[1];
  const float* sd = (const float*)d_in[2];
  const float* dd = (const float*)d_in[3];
  float* out = (float*)d_out;
  float* ws = (float*)d_ws;

  if (ws_size >= (size_t)WS_NEED) {
    char* pq = (char*)d_ws + WS_PQ_B;
    char* pp = (char*)d_ws + WS_PP_B;
    hipLaunchKernelGGL(k_prep, dim3(544), dim3(256), 0, stream, kd, dd, ws, pq, pp);
    hipLaunchKernelGGL(k_match3, dim3(512), dim3(256), 0, stream,
                       pp, pq, ws, (float4*)(ws + WS_PART));
    hipLaunchKernelGGL(k_weights2, dim3(BN * NKP / 4), dim3(256), 0, stream,
                       pp, pq, ks, sd, ws, (const float4*)(ws + WS_PART), out);
  } else {
    hipLaunchKernelGGL(k_rnorm_src, dim3(BN * NKP / 256), dim3(256), 0, stream, kd, ws);
    hipLaunchKernelGGL(k_rnorm_tgt, dim3(BN * HWPX / 256), dim3(256), 0, stream, dd, ws);
    hipLaunchKernelGGL(k_match, dim3(FB_PSPLIT, NKP / FB_NT, BN), dim3(256), 0, stream,
                       kd, dd, ws, (float4*)(ws + WS_PART));
    hipLaunchKernelGGL(k_coords, dim3(BN * NKP / 256), dim3(256), 0, stream,
                       (const float4*)(ws + WS_PART), out);
    hipLaunchKernelGGL(k_weights, dim3(BN * NKP / 4), dim3(256), 0, stream,
                       kd, dd, ks, sd, ws, out);
  }
}

// Round 18
// 70.645 us; speedup vs baseline: 2.8143x; 1.0011x over previous
//
#include <hip/hip_runtime.h>
#include <math.h>

#define BN 4
#define CDIM 256
#define NKP 1024
#define HH 128
#define WW 128
#define HWPX (HH*WW)

#define PSPLIT 16
#define PPB 1024
#define NT 128

// ---- workspace layout ----
#define WS_RS 0
#define WS_RT (WS_RS + BN*NKP)
#define WS_PART (WS_RT + BN*HWPX)          // float4[BN*NKP*PSPLIT]
#define WS_PQ_B 1327104u                   // [b][kc][64 frag]x1024B = 4 MB region
#define WS_PP_B 5521408u                   // [b][kc][1024 frag]x1024B (HI ONLY) = 32 MB
#define WS_NEED 39075840u

typedef __attribute__((ext_vector_type(8)))  _Float16 v8h;
typedef __attribute__((ext_vector_type(4)))  float v4f;

#define GETJ(v, j) ((j) == 0 ? (v).x : (j) == 1 ? (v).y : (j) == 2 ? (v).z : (v).w)

// ======================= fast path =======================

// Fused prep: 2 threads per element; even/odd lanes split channels into
// halves (4 kc-planes each); norm combined via shfl_xor(1).
// Blocks 0..511: P (dd) -> f16 HI. Blocks 512..543: Q (kd) -> f16 HI.
// Fragment block = 1024 B: [4 ko][16 col][16 B]; frag index = col>>4.
__global__ __launch_bounds__(256) void k_prep(const float* __restrict__ kd,
                                              const float* __restrict__ dd,
                                              float* __restrict__ wsf,
                                              char* __restrict__ pq,
                                              char* __restrict__ pp) {
  const int tid = threadIdx.x;
  const int half = tid & 1;
  const int kc0 = half * 4;
  if (blockIdx.x < 512) {
    int id = blockIdx.x;                 // 512 = b*128 + mb
    int b = id >> 7;
    int m = (id & 127) * 128 + (tid >> 1);
    const float* p = dd + (size_t)(2 * b + 1) * CDIM * HWPX + m;
    char* mb = pp + (size_t)b * 8388608 + (m >> 4) * 1024 + (m & 15) * 16;
    float s = 0.f;
#pragma unroll
    for (int kc = 0; kc < 4; ++kc) {
#pragma unroll
      for (int ko = 0; ko < 4; ++ko) {
        v8h hi;
#pragma unroll
        for (int j = 0; j < 8; ++j) {
          float v = p[(size_t)((kc0 + kc) * 32 + ko * 8 + j) * HWPX];
          s = fmaf(v, v, s);
          hi[j] = (_Float16)(v * 32.f);
        }
        *(v8h*)(mb + (size_t)(kc0 + kc) * 1048576 + ko * 256) = hi;
      }
    }
    s += __shfl_xor(s, 1, 64);
    if (half == 0) wsf[WS_RT + b * HWPX + m] = 1.f / fmaxf(sqrtf(s), 1e-12f);
  } else {
    int id = blockIdx.x - 512;           // 32 = b*8 + nb
    int b = id >> 3;
    int n = (id & 7) * 128 + (tid >> 1);
    const float* p = kd + (size_t)(2 * b) * CDIM * NKP + n;
    char* qb = pq + (size_t)b * 1048576 + (n >> 4) * 1024 + (n & 15) * 16;
    float s = 0.f;
#pragma unroll
    for (int kc = 0; kc < 4; ++kc) {
#pragma unroll
      for (int ko = 0; ko < 4; ++ko) {
        v8h hi;
#pragma unroll
        for (int j = 0; j < 8; ++j) {
          float v = p[(size_t)((kc0 + kc) * 32 + ko * 8 + j) * NKP];
          s = fmaf(v, v, s);
          hi[j] = (_Float16)(v * 32.f);
        }
        *(v8h*)(qb + (size_t)(kc0 + kc) * 131072 + ko * 256) = hi;
      }
    }
    s += __shfl_xor(s, 1, 64);
    if (half == 0) wsf[WS_RS + b * NKP + n] = 1.f / fmaxf(sqrtf(s), 1e-12f);
  }
}

// Zero-barrier-loop fused MFMA GEMM + fixed-shift softmax, 1-term f16
// (banked r16 config, 70.7 us total): NT=128, Qh plane wholly in 64 KB LDS,
// grid 512 = exactly 2 blocks/CU, A/B double-buffered fragments.
#define LOADT(ph, qh, t) do {                                                  \
  const int pt_ = (t) >> 3, kc_ = (t) & 7;                                     \
  const char* Pb_ = ppb + (size_t)kc_ * 1048576 + (size_t)(frp + pt_ * 8) * 1024; \
  const char* Qs_ = QSM + kc_ * 8192 + wn * 4096;                              \
  _Pragma("unroll")                                                            \
  for (int f_ = 0; f_ < 4; ++f_) {                                             \
    ph[f_] = *(const v8h*)(Pb_ + f_ * 1024 + lane16);                          \
    qh[f_] = *(const v8h*)(Qs_ + f_ * 1024 + lane16);                          \
  }                                                                            \
} while (0)

#define MFMAT(ph, qh)                                                          \
  __builtin_amdgcn_s_setprio(1);                                               \
  _Pragma("unroll")                                                            \
  for (int s_ = 0; s_ < 4; ++s_) {                                             \
    _Pragma("unroll")                                                          \
    for (int f_ = 0; f_ < 4; ++f_) {                                           \
      acc[f_][s_] = __builtin_amdgcn_mfma_f32_16x16x32_f16(ph[f_], qh[s_], acc[f_][s_], 0, 0, 0); \
    }                                                                          \
  }                                                                            \
  __builtin_amdgcn_s_setprio(0);

__global__ __launch_bounds__(256, 2) void k_match3(const char* __restrict__ pp,
                                                   const char* __restrict__ pq,
                                                   const float* __restrict__ wsf,
                                                   float4* __restrict__ partials) {
  __shared__ __align__(16) char QSM[65536];
  const int tid = threadIdx.x;
  const int w = tid >> 6, lane = tid & 63;
  const int l15 = lane & 15, lq = lane >> 4;
  const int wm = w & 1, wn = w >> 1;

  // XCD-chunked grid: fid = b*128 + ps*8 + nt; XCD x owns b = x>>1, 8 ps values.
  const int raw = blockIdx.x;
  const int fid = (raw & 7) * 64 + (raw >> 3);
  const int b = fid >> 7, ps = (fid >> 3) & 15, nt = fid & 7;
  const int n0b = nt * NT;

  const char* ppb = pp + (size_t)b * 8388608;
  const char* pqb = pq + (size_t)b * 1048576;
  const float* rtp = wsf + WS_RT + b * HWPX + ps * PPB;
  const float* rsp = wsf + WS_RS + b * NKP;

  const int frp = ps * 64 + wm * 4;
  const unsigned lane16 = (unsigned)lane * 16;

  // ---- stage Qh plane (block's 128 n, all 8 kc) into LDS: 64 KB ----
#pragma unroll
  for (int j = 0; j < 16; ++j) {
    int off = j * 4096 + tid * 16;
    int kc = off >> 13, rem = off & 8191;   // rem = f*1024 + l16, f<8
    *(float4*)(QSM + off) =
        *(const float4*)(pqb + (size_t)kc * 131072 + (size_t)(nt * 8) * 1024 + rem);
  }
  __syncthreads();

  float rs100[4];
#pragma unroll
  for (int s = 0; s < 4; ++s)
    rs100[s] = rsp[n0b + wn * 64 + s * 16 + l15] * (100.f / 1024.f);

  float ls[4], su[4], sv[4];
#pragma unroll
  for (int s = 0; s < 4; ++s) { ls[s] = su[s] = sv[s] = 0.f; }

  v4f acc[4][4];
#pragma unroll
  for (int f = 0; f < 4; ++f)
#pragma unroll
    for (int s = 0; s < 4; ++s)
#pragma unroll
      for (int e = 0; e < 4; ++e) acc[f][s][e] = 0.f;

  const float ubase = (float)(wm * 64 + lq * 4);
  const float vbase = (float)(ps * 8);

  v8h phA[4], qhA[4], phB[4], qhB[4];
  LOADT(phA, qhA, 0);

  for (int t2 = 0; t2 < 64; t2 += 2) {
    LOADT(phB, qhB, t2 + 1);
    MFMAT(phA, qhA);
    if (t2 + 2 < 64) LOADT(phA, qhA, t2 + 2);
    MFMAT(phB, qhB);

    if (((t2 + 1) & 7) == 7) {           // K complete for this 128-px tile
      const int pt = t2 >> 3;
      const float vb = vbase + (float)pt;
      float4 rt4[4];
#pragma unroll
      for (int f = 0; f < 4; ++f)
        rt4[f] = *(const float4*)(rtp + pt * 128 + wm * 64 + f * 16 + lq * 4);
#pragma unroll
      for (int s = 0; s < 4; ++s) {
        float te = 0.f, tu = 0.f;
#pragma unroll
        for (int f = 0; f < 4; ++f)
#pragma unroll
          for (int e = 0; e < 4; ++e) {
            float x = __expf(fmaf(acc[f][s][e], rs100[s] * GETJ(rt4[f], e), -100.f));
            te += x;
            tu = fmaf(x, ubase + (float)(f * 16 + e), tu);
            acc[f][s][e] = 0.f;
          }
        ls[s] += te;
        su[s] += tu;
        sv[s] = fmaf(vb, te, sv[s]);
      }
    }
  }

  // merge 8 partials (wm x lq) per keypoint — plain sums
  __syncthreads();                 // all Qh reads done; reuse LDS as merge buf
  float4* red = (float4*)QSM;      // [128 n][8 slots]
#pragma unroll
  for (int s = 0; s < 4; ++s)
    red[(wn * 64 + s * 16 + l15) * 8 + wm * 4 + lq] = make_float4(ls[s], su[s], sv[s], 0.f);
  __syncthreads();
  if (tid < NT) {
    float L = 0.f, SU = 0.f, SV = 0.f;
#pragma unroll
    for (int i = 0; i < 8; ++i) {
      float4 q = red[tid * 8 + i];
      L += q.x; SU += q.y; SV += q.z;
    }
    partials[(size_t)(b * NKP + n0b + tid) * PSPLIT + ps] = make_float4(L, SU, SV, 0.f);
  }
}

// Fused partial-merge + coords + bilinear weights. Desc dot gathered from the
// prepped f16 arrays (pp/pq): lane = corner(lane>>4) x chunk(lane&15, x2);
// 16-B loads replace per-channel 4-B gathers (~5x less cacheline traffic).
__global__ __launch_bounds__(256) void k_weights2(const char* __restrict__ pp,
                                                  const char* __restrict__ pq,
                                                  const float* __restrict__ ks,
                                                  const float* __restrict__ sd,
                                                  const float* __restrict__ ws_in,
                                                  const float4* __restrict__ partials,
                                                  float* __restrict__ out) {
  int wid = blockIdx.x * 4 + (threadIdx.x >> 6);
  int lane = threadIdx.x & 63;
  int b = wid >> 10, n = wid & (NKP - 1);

  float L = 0.f, SU = 0.f, SV = 0.f;
  if (lane < PSPLIT) {
    float4 q = partials[(size_t)wid * PSPLIT + lane];
    L = q.x; SU = q.y; SV = q.z;
  }
#pragma unroll
  for (int o = 1; o < 64; o <<= 1) {
    L += __shfl_xor(L, o, 64);
    SU += __shfl_xor(SU, o, 64);
    SV += __shfl_xor(SV, o, 64);
  }
  float pu = SU / L, pv = SV / L;
  if (lane == 0) {
    out[wid * 2 + 0] = pu;
    out[wid * 2 + 1] = pv;
  }

  float x = pu * (128.f / 127.f) - 0.5f;
  float y = pv * (128.f / 127.f) - 0.5f;
  float x0 = floorf(x), y0 = floorf(y);
  float wx1 = x - x0, wx0 = 1.f - wx1;
  float wy1 = y - y0, wy0 = 1.f - wy1;

  float xs[4] = {x0, x0 + 1.f, x0, x0 + 1.f};
  float ys[4] = {y0, y0, y0 + 1.f, y0 + 1.f};
  float wsc[4] = {wx0 * wy0, wx1 * wy0, wx0 * wy1, wx1 * wy1};
  float cw[4];
  int co[4];
#pragma unroll
  for (int k = 0; k < 4; ++k) {
    bool inb = (xs[k] >= 0.f) && (xs[k] < (float)WW) && (ys[k] >= 0.f) && (ys[k] < (float)HH);
    cw[k] = inb ? wsc[k] : 0.f;
    int cx = min(max((int)xs[k], 0), WW - 1);
    int cy = min(max((int)ys[k], 0), HH - 1);
    co[k] = cy * WW + cx;
  }

  // gather dot from prepped f16 (both operands x32 -> descale by 1/1024)
  const int k = lane >> 4;
  const int m = co[k];
  const char* qb = pq + (size_t)b * 1048576 + (n >> 4) * 1024 + (n & 15) * 16;
  const char* pb = pp + (size_t)b * 8388608 + (m >> 4) * 1024 + (m & 15) * 16;
  float accd = 0.f;
#pragma unroll
  for (int i = 0; i < 2; ++i) {
    int chunk = (lane & 15) + 16 * i;
    int kc = chunk >> 2, ko = chunk & 3;
    v8h t8 = *(const v8h*)(pb + (size_t)kc * 1048576 + ko * 256);
    v8h s8 = *(const v8h*)(qb + (size_t)kc * 131072 + ko * 256);
#pragma unroll
    for (int j = 0; j < 8; ++j) accd = fmaf((float)t8[j], (float)s8[j], accd);
  }
  accd *= cw[k];
#pragma unroll
  for (int o = 32; o; o >>= 1) accd += __shfl_xor(accd, o, 64);

  if (lane == 0) {
    const float* ssc = sd + (size_t)(2 * b + 1) * HWPX;
    float psc = cw[0] * ssc[co[0]] + cw[1] * ssc[co[1]] + cw[2] * ssc[co[2]] + cw[3] * ssc[co[3]];
    float dms = accd * ws_in[WS_RS + b * NKP + n] * (1.f / (1024.f * 256.f));
    float w = 0.5f * (dms + 1.f) * ks[(size_t)(2 * b) * NKP + n] * psc;
    out[BN * NKP * 2 + b * NKP + n] = w;
  }
}

// ======================= fallback path (round-4, passed) =======================

#define FB_NT 128
#define FB_PSPLIT 16
#define FB_PPB 1024
#define MT 256
#define KC 32
#define PT_STEPS (FB_PPB/MT)
#define CHUNKS (CDIM/KC)
#define KROW 80
#define PH_OFF 0
#define PL_OFF 20480
#define QH_OFF 40960
#define QL_OFF 51200
#define RSL_OFF 61440
#define RTL_OFF 61952
#define SM_BYTES 62976

__global__ __launch_bounds__(256) void k_rnorm_src(const float* __restrict__ kd,
                                                   float* __restrict__ ws) {
  int idx = blockIdx.x * 256 + threadIdx.x;
  int b = idx >> 10, n = idx & (NKP - 1);
  const float* p = kd + (size_t)(2 * b) * CDIM * NKP + n;
  float s = 0.f;
  for (int c = 0; c < CDIM; ++c) { float v = p[(size_t)c * NKP]; s = fmaf(v, v, s); }
  ws[WS_RS + idx] = 1.f / fmaxf(sqrtf(s), 1e-12f);
}

__global__ __launch_bounds__(256) void k_rnorm_tgt(const float* __restrict__ dd,
                                                   float* __restrict__ ws) {
  int idx = blockIdx.x * 256 + threadIdx.x;
  int b = idx >> 14, m = idx & (HWPX - 1);
  const float* p = dd + (size_t)(2 * b + 1) * CDIM * HWPX + m;
  float s = 0.f;
  for (int c = 0; c < CDIM; ++c) { float v = p[(size_t)c * HWPX]; s = fmaf(v, v, s); }
  ws[WS_RT + idx] = 1.f / fmaxf(sqrtf(s), 1e-12f);
}

__global__ __launch_bounds__(256, 2) void k_match(const float* __restrict__ kd,
                                                  const float* __restrict__ dd,
                                                  const float* __restrict__ wsp,
                                                  float4* __restrict__ partials) {
  __shared__ __align__(16) char SM[SM_BYTES];
  const int tid = threadIdx.x;
  const int w = tid >> 6, lane = tid & 63;
  const int l15 = lane & 15, lq = lane >> 4;
  const int ps = blockIdx.x, nt = blockIdx.y, b = blockIdx.z;
  const int n0b = nt * FB_NT;
  const int p0 = ps * FB_PPB;

  const float* Ag = kd + (size_t)(2 * b) * CDIM * NKP;
  const float* Bg = dd + (size_t)(2 * b + 1) * CDIM * HWPX;
  const float* rs = wsp + WS_RS + b * NKP;
  const float* rt = wsp + WS_RT + b * HWPX;

  float* rsl = (float*)(SM + RSL_OFF);
  float* rtl = (float*)(SM + RTL_OFF);
  if (tid < FB_NT) rsl[tid] = rs[n0b + tid] * 3.125f;

  const int koct = tid & 3;
  const int mq4 = (tid >> 2) * 4;

  float mx[8], ls[8], su[8], sv[8];
#pragma unroll
  for (int s = 0; s < 8; ++s) { mx[s] = -INFINITY; ls[s] = su[s] = sv[s] = 0.f; }

  const float ubase = (float)((w & 1) * 64 + lq * 4);

  for (int pt = 0; pt < PT_STEPS; ++pt) {
    const int pm0 = p0 + pt * MT;
    __syncthreads();
    rtl[tid] = rt[pm0 + tid] * 32.f;

    v4f acc[4][8];
#pragma unroll
    for (int f = 0; f < 4; ++f)
#pragma unroll
      for (int s = 0; s < 8; ++s)
#pragma unroll
        for (int e = 0; e < 4; ++e) acc[f][s][e] = 0.f;

    for (int kc = 0; kc < CHUNKS; ++kc) {
      __syncthreads();
      {
        const float* Bk = Bg + (size_t)(kc * KC + koct * 8) * HWPX + pm0 + mq4;
        float4 r[8];
#pragma unroll
        for (int rr = 0; rr < 8; ++rr) r[rr] = *(const float4*)(Bk + (size_t)rr * HWPX);
        float4 sc4 = *(const float4*)(rtl + mq4);
#pragma unroll
        for (int j = 0; j < 4; ++j) {
          const float scj = GETJ(sc4, j);
          v8h hi, lo;
#pragma unroll
          for (int rr = 0; rr < 8; ++rr) {
            float v = GETJ(r[rr], j) * scj;
            _Float16 hh = (_Float16)v;
            hi[rr] = hh;
            lo[rr] = (_Float16)(v - (float)hh);
          }
          *(v8h*)(SM + PH_OFF + (mq4 + j) * KROW + koct * 16) = hi;
          *(v8h*)(SM + PL_OFF + (mq4 + j) * KROW + koct * 16) = lo;
        }
      }
      if (tid < 128) {
        const int nq4 = (tid >> 2) * 4;
        const float* Ak = Ag + (size_t)(kc * KC + koct * 8) * NKP + n0b + nq4;
        float4 r[8];
#pragma unroll
        for (int rr = 0; rr < 8; ++rr) r[rr] = *(const float4*)(Ak + (size_t)rr * NKP);
        float4 sc4 = *(const float4*)(rsl + nq4);
#pragma unroll
        for (int j = 0; j < 4; ++j) {
          const float scj = GETJ(sc4, j);
          v8h hi, lo;
#pragma unroll
          for (int rr = 0; rr < 8; ++rr) {
            float v = GETJ(r[rr], j) * scj;
            _Float16 hh = (_Float16)v;
            hi[rr] = hh;
            lo[rr] = (_Float16)(v - (float)hh);
          }
          *(v8h*)(SM + QH_OFF + (nq4 + j) * KROW + koct * 16) = hi;
          *(v8h*)(SM + QL_OFF + (nq4 + j) * KROW + koct * 16) = lo;
        }
      }
      __syncthreads();

      v8h PHf[4], PLf[4];
#pragma unroll
      for (int f = 0; f < 4; ++f) {
        const int row = w * 64 + f * 16 + l15;
        PHf[f] = *(const v8h*)(SM + PH_OFF + row * KROW + lq * 16);
        PLf[f] = *(const v8h*)(SM + PL_OFF + row * KROW + lq * 16);
      }
#pragma unroll
      for (int s = 0; s < 8; ++s) {
        const int col = s * 16 + l15;
        v8h qh = *(const v8h*)(SM + QH_OFF + col * KROW + lq * 16);
        v8h ql = *(const v8h*)(SM + QL_OFF + col * KROW + lq * 16);
#pragma unroll
        for (int f = 0; f < 4; ++f) {
          acc[f][s] = __builtin_amdgcn_mfma_f32_16x16x32_f16(PHf[f], qh, acc[f][s], 0, 0, 0);
          acc[f][s] = __builtin_amdgcn_mfma_f32_16x16x32_f16(PLf[f], qh, acc[f][s], 0, 0, 0);
          acc[f][s] = __builtin_amdgcn_mfma_f32_16x16x32_f16(PHf[f], ql, acc[f][s], 0, 0, 0);
        }
      }
    }

    const float vb = (float)((pm0 >> 7) + (w >> 1));
#pragma unroll
    for (int s = 0; s < 8; ++s) {
      float tm = -INFINITY;
#pragma unroll
      for (int f = 0; f < 4; ++f)
#pragma unroll
        for (int e = 0; e < 4; ++e) tm = fmaxf(tm, acc[f][s][e]);
      float nm = fmaxf(mx[s], tm);
      float scf = __expf(mx[s] - nm);
      float te = 0.f, tu = 0.f;
#pragma unroll
      for (int f = 0; f < 4; ++f)
#pragma unroll
        for (int e = 0; e < 4; ++e) {
          float x = __expf(acc[f][s][e] - nm);
          te += x;
          tu = fmaf(x, ubase + (float)(f * 16 + e), tu);
        }
      ls[s] = ls[s] * scf + te;
      su[s] = su[s] * scf + tu;
      sv[s] = sv[s] * scf + vb * te;
      mx[s] = nm;
    }
  }

  __syncthreads();
  float4* red = (float4*)SM;
#pragma unroll
  for (int s = 0; s < 8; ++s)
    red[(s * 16 + l15) * 16 + w * 4 + lq] = make_float4(mx[s], ls[s], su[s], sv[s]);
  __syncthreads();
  if (tid < FB_NT) {
    float M = -INFINITY, L = 0.f, SU = 0.f, SV = 0.f;
#pragma unroll
    for (int i = 0; i < 16; ++i) {
      float4 q = red[tid * 16 + i];
      float nm2 = fmaxf(M, q.x);
      float e1 = __expf(M - nm2), e2 = __expf(q.x - nm2);
      L = L * e1 + q.y * e2; SU = SU * e1 + q.z * e2; SV = SV * e1 + q.w * e2;
      M = nm2;
    }
    partials[(size_t)(b * NKP + n0b + tid) * FB_PSPLIT + ps] = make_float4(M, L, SU, SV);
  }
}

__global__ __launch_bounds__(256) void k_coords(const float4* __restrict__ partials,
                                                float* __restrict__ out) {
  int row = blockIdx.x * 256 + threadIdx.x;
  float M = -INFINITY, L = 0.f, SU = 0.f, SV = 0.f;
  for (int i = 0; i < FB_PSPLIT; ++i) {
    float4 q = partials[(size_t)row * FB_PSPLIT + i];
    float nm = fmaxf(M, q.x);
    float e1 = __expf(M - nm), e2 = __expf(q.x - nm);
    L = L * e1 + q.y * e2; SU = SU * e1 + q.z * e2; SV = SV * e1 + q.w * e2;
    M = nm;
  }
  out[row * 2 + 0] = SU / L;
  out[row * 2 + 1] = SV / L;
}

__global__ __launch_bounds__(256) void k_weights(const float* __restrict__ kd,
                                                 const float* __restrict__ dd,
                                                 const float* __restrict__ ks,
                                                 const float* __restrict__ sd,
                                                 const float* __restrict__ ws_in,
                                                 float* __restrict__ out) {
  int wid = blockIdx.x * 4 + (threadIdx.x >> 6);
  int lane = threadIdx.x & 63;
  int b = wid >> 10, n = wid & (NKP - 1);

  float pu = out[wid * 2 + 0];
  float pv = out[wid * 2 + 1];
  float x = pu * (128.f / 127.f) - 0.5f;
  float y = pv * (128.f / 127.f) - 0.5f;
  float x0 = floorf(x), y0 = floorf(y);
  float wx1 = x - x0, wx0 = 1.f - wx1;
  float wy1 = y - y0, wy0 = 1.f - wy1;

  float xs[4] = {x0, x0 + 1.f, x0, x0 + 1.f};
  float ys[4] = {y0, y0, y0 + 1.f, y0 + 1.f};
  float wsc[4] = {wx0 * wy0, wx1 * wy0, wx0 * wy1, wx1 * wy1};
  float cw[4];
  int co[4];
#pragma unroll
  for (int k = 0; k < 4; ++k) {
    bool inb = (xs[k] >= 0.f) && (xs[k] < (float)WW) && (ys[k] >= 0.f) && (ys[k] < (float)HH);
    cw[k] = inb ? wsc[k] : 0.f;
    int cx = min(max((int)xs[k], 0), WW - 1);
    int cy = min(max((int)ys[k], 0), HH - 1);
    co[k] = cy * WW + cx;
  }

  const float* tgt = dd + (size_t)(2 * b + 1) * CDIM * HWPX;
  const float* srcd = kd + (size_t)(2 * b) * CDIM * NKP;
  float accd = 0.f;
  for (int c = lane; c < CDIM; c += 64) {
    const float* tc = tgt + (size_t)c * HWPX;
    float pd = cw[0] * tc[co[0]] + cw[1] * tc[co[1]] + cw[2] * tc[co[2]] + cw[3] * tc[co[3]];
    float sc = srcd[(size_t)c * NKP + n];
    accd = fmaf(sc, pd, accd);
  }
#pragma unroll
  for (int o = 32; o; o >>= 1) accd += __shfl_xor(accd, o, 64);

  if (lane == 0) {
    const float* ssc = sd + (size_t)(2 * b + 1) * HWPX;
    float psc = cw[0] * ssc[co[0]] + cw[1] * ssc[co[1]] + cw[2] * ssc[co[2]] + cw[3] * ssc[co[3]];
    float dms = accd * ws_in[WS_RS + b * NKP + n] * (1.f / (float)CDIM);
    float w = 0.5f * (dms + 1.f) * ks[(size_t)(2 * b) * NKP + n] * psc;
    out[BN * NKP * 2 + b * NKP + n] = w;
  }
}

extern "C" void kernel_launch(void* const* d_in, const int* in_sizes, int n_in,
                              void* d_out, int out_size, void* d_ws, size_t ws_size,
                              hipStream_t stream) {
  const float* ks = (const float*)d_in[0];
  const float* kd = (const float*)d_in[1];
  const float* sd = (const float*)d_in[2];
  const float* dd = (const float*)d_in[3];
  float* out = (float*)d_out;
  float* ws = (float*)d_ws;

  if (ws_size >= (size_t)WS_NEED) {
    char* pq = (char*)d_ws + WS_PQ_B;
    char* pp = (char*)d_ws + WS_PP_B;
    hipLaunchKernelGGL(k_prep, dim3(544), dim3(256), 0, stream, kd, dd, ws, pq, pp);
    hipLaunchKernelGGL(k_match3, dim3(512), dim3(256), 0, stream,
                       pp, pq, ws, (float4*)(ws + WS_PART));
    hipLaunchKernelGGL(k_weights2, dim3(BN * NKP / 4), dim3(256), 0, stream,
                       pp, pq, ks, sd, ws, (const float4*)(ws + WS_PART), out);
  } else {
    hipLaunchKernelGGL(k_rnorm_src, dim3(BN * NKP / 256), dim3(256), 0, stream, kd, ws);
    hipLaunchKernelGGL(k_rnorm_tgt, dim3(BN * HWPX / 256), dim3(256), 0, stream, dd, ws);
    hipLaunchKernelGGL(k_match, dim3(FB_PSPLIT, NKP / FB_NT, BN), dim3(256), 0, stream,
                       kd, dd, ws, (float4*)(ws + WS_PART));
    hipLaunchKernelGGL(k_coords, dim3(BN * NKP / 256), dim3(256), 0, stream,
                       (const float4*)(ws + WS_PART), out);
    hipLaunchKernelGGL(k_weights, dim3(BN * NKP / 4), dim3(256), 0, stream,
                       kd, dd, ks, sd, ws, out);
  }
}